// Round 11
// baseline (2013.721 us; speedup 1.0000x reference)
//
#include <hip/hip_runtime.h>
#include <hip/hip_bf16.h>
#include <math.h>

// Problem dims (fixed)
#define B   64
#define NN  196
#define HH  512
#define EE  512
#define AA  512
#define VV  20000
#define LL  20

typedef __attribute__((ext_vector_type(8))) short bf16x8;
typedef __attribute__((ext_vector_type(4))) float floatx4;

__device__ __forceinline__ float tanh_fast(float x) {
  float e2 = __expf(2.f * x);
  return 1.f - 2.f / (e2 + 1.f);
}
__device__ __forceinline__ float sigmoid_fast(float x) {
  return 1.f / (1.f + __expf(-x));
}
__device__ __forceinline__ float bf2f(unsigned short u) {
  return __uint_as_float(((unsigned)u) << 16);
}
__device__ __forceinline__ unsigned short f2bf(float v) {
  __hip_bfloat16 h = __float2bfloat16(v);
  return *reinterpret_cast<unsigned short*>(&h);
}

// Chunk-XOR LDS slot for BK=32 rows (4 x 16B chunks): c' = q4 ^ ((row>>1)&3).
// Measured (round 6): SQ_LDS_BANK_CONFLICT 6.4M -> 0 on the big GEMMs.
__device__ __forceinline__ int ldsw(int row, int q4) {
  return (row * 4 + (q4 ^ ((row >> 1) & 3))) * 8;
}
// Chunk-XOR for BK=64 rows (8 chunks). gates path only.
__device__ __forceinline__ int ldsw8(int row, int q8) {
  return (row * 8 + (q8 ^ (row & 7))) * 8;
}

// ---------------------------------------------------------------------------
// bf16 MFMA GEMM (EXACT round-6/9/10 version; measured: logits 88us, FETCH
// 24MB, 0 conflicts). 128x128 tile, BK=32, 256 thr. gridMX==2: XCD-grouped.
// outMode==0 fp32; ==1 logits scatter; ==2 bf16 store.
// ---------------------------------------------------------------------------
__global__ __launch_bounds__(256) void gemm_mfma_bt(
    const unsigned short* __restrict__ Xb, const unsigned short* __restrict__ Wb,
    const float* __restrict__ bias, float* __restrict__ C,
    int M, int N, int K, int lda, int ldC, int outMode, int gridMX) {
  __shared__ unsigned short As[128 * 32];
  __shared__ unsigned short Bs[128 * 32];
  const int tid = threadIdx.x;
  const int lane = tid & 63;
  const int l15 = lane & 15;
  const int q = lane >> 4;
  const int wv = tid >> 6;
  const int wm = (wv >> 1) * 64;
  const int wn = (wv & 1) * 64;
  int mBase, nBase;
  if (gridMX == 2) {
    const int MT = (M + 127) >> 7, NT = (N + 127) >> 7;
    int wg = blockIdx.x;
    int xcd = wg & 7, idx = wg >> 3;
    int kk = idx / MT, mi = idx - kk * MT;
    int p = kk * 8 + xcd;
    if (p >= NT) return;
    mBase = mi * 128;
    nBase = p * 128;
  } else {
    mBase = blockIdx.y * 128;
    nBase = blockIdx.x * 128;
  }

  const int c0 = tid, c1 = tid + 256;
  const int r0 = c0 >> 2, q0 = c0 & 3;
  const int r1 = c1 >> 2, q1 = c1 & 3;
  const int s0 = ldsw(r0, q0), s1 = ldsw(r1, q1);

  floatx4 zero = {0.f, 0.f, 0.f, 0.f};
  floatx4 acc[4][4];
#pragma unroll
  for (int i = 0; i < 4; ++i)
#pragma unroll
    for (int j = 0; j < 4; ++j) acc[i][j] = zero;

  for (int k0 = 0; k0 < K; k0 += 32) {
    uint4 a0 = *(const uint4*)(Xb + (size_t)(mBase + r0) * lda + k0 + q0 * 8);
    uint4 a1 = *(const uint4*)(Xb + (size_t)(mBase + r1) * lda + k0 + q1 * 8);
    uint4 b0 = *(const uint4*)(Wb + (size_t)(nBase + r0) * K + k0 + q0 * 8);
    uint4 b1 = *(const uint4*)(Wb + (size_t)(nBase + r1) * K + k0 + q1 * 8);
    __syncthreads();
    *(uint4*)&As[s0] = a0;
    *(uint4*)&As[s1] = a1;
    *(uint4*)&Bs[s0] = b0;
    *(uint4*)&Bs[s1] = b1;
    __syncthreads();
    bf16x8 af[4], bfv[4];
#pragma unroll
    for (int i = 0; i < 4; ++i)
      af[i] = *(const bf16x8*)&As[ldsw(wm + i * 16 + l15, q)];
#pragma unroll
    for (int j = 0; j < 4; ++j)
      bfv[j] = *(const bf16x8*)&Bs[ldsw(wn + j * 16 + l15, q)];
#pragma unroll
    for (int i = 0; i < 4; ++i)
#pragma unroll
      for (int j = 0; j < 4; ++j)
        acc[i][j] = __builtin_amdgcn_mfma_f32_16x16x32_bf16(af[i], bfv[j],
                                                            acc[i][j], 0, 0, 0);
  }

#pragma unroll
  for (int i = 0; i < 4; ++i) {
#pragma unroll
    for (int j = 0; j < 4; ++j) {
#pragma unroll
      for (int p = 0; p < 4; ++p) {
        int m = mBase + wm + i * 16 + q * 4 + p;
        int n = nBase + wn + j * 16 + l15;
        if (m < M && n < N) {
          float v = acc[i][j][p];
          if (bias) v += bias[n];
          if (outMode == 1) {
            size_t idx = (size_t)(m & 63) * ((size_t)LL * VV) +
                         (size_t)((m >> 6) + 1) * VV + n;
            C[idx] = v;
          } else if (outMode == 2) {
            ((unsigned short*)C)[(size_t)m * ldC + n] = f2bf(v);
          } else {
            C[(size_t)m * ldC + n] = v;
          }
        }
      }
    }
  }
}

// ---------------------------------------------------------------------------
// decoder_persist: ALL 19 timesteps in ONE dispatch. 80 blocks x 512 thr,
// co-resident (80 <= 256 CUs; no kernel-boundary cache invalidation between
// steps -> Wgi/dec_Wp/enc_projb slices stay L2-warm). Flag protocol proven in
// round 10, now bidirectional:
//   fh[g]  (g=0..15): consumer g finished writing its h_{s} slice  (value s)
//   fctx[b](b=0..63): producer b finished writing ctx_s            (value s+1)
// Step DAG: fh(s) -> producers{dec,scores,softmax,ctx} -> fctx(s+1)
//           fh(s) -> consumers ph0 (h-half GEMM) -> wait fctx(s+1) -> ph1
//           -> pointwise -> fh(s+1).  Acyclic; deadlock-free by co-residency.
// ---------------------------------------------------------------------------
__global__ __launch_bounds__(512) void decoder_persist(
    const unsigned short* __restrict__ enc_projb,
    const unsigned short* __restrict__ encOutb,
    const unsigned short* __restrict__ dec_Wp,  // [(k/8)*512+a] 8-chunk bf16
    const float* __restrict__ dec_b, const float* __restrict__ eW,
    const float* __restrict__ eb,
    const unsigned short* __restrict__ Wgi,     // [2048][1024] interleaved
    const float* __restrict__ gates_all_,       // [19][64][2048] interleaved
    float* __restrict__ c,
    unsigned short* __restrict__ xcat2,         // 2 x [128][1024] bf16
    unsigned short* __restrict__ hb,            // [1280][512] bf16
    int* __restrict__ flags) {                  // [0..63]=fctx, [64..79]=fh
  const int tid = threadIdx.x;
  __shared__ __align__(16) char smem[58368];
  int* fctx = flags;
  int* fh = flags + 64;

  if (blockIdx.x < 64) {
    // ======================= ATTENTION PRODUCER =======================
    const int b = blockIdx.x;
    float* hs = (float*)smem;              // 2048 B
    float* sdec = (float*)(smem + 2048);   // 2048 B
    float* sw = (float*)(smem + 4096);     // 1024 B (196 used)
    float* tmp = (float*)(smem + 5120);    // 1024 B
    float* cp = (float*)(smem + 6144);     // 4096 B
    const int wvv = tid >> 6, lane = tid & 63;
    float ew8[8];
#pragma unroll
    for (int j = 0; j < 8; ++j) ew8[j] = eW[lane * 8 + j];
    float eb0 = eb[0];
    float dbv = dec_b[tid];

    for (int s = 0; s < 19; ++s) {
      unsigned short* xcur = xcat2 + (size_t)(s & 1) * 131072;
      if (s > 0) {
        if (tid < 16) {
          while (__hip_atomic_load(&fh[tid], __ATOMIC_ACQUIRE,
                                   __HIP_MEMORY_SCOPE_AGENT) < s)
            __builtin_amdgcn_s_sleep(2);
        }
        __syncthreads();
      }
      hs[tid] = bf2f(xcur[(size_t)b * 1024 + tid]);
      __syncthreads();
      {
        float dacc = dbv;
#pragma unroll 4
        for (int kg = 0; kg < 64; ++kg) {
          bf16x8 w8 = *(const bf16x8*)(dec_Wp + (size_t)((kg << 9) + tid) * 8);
#pragma unroll
          for (int j = 0; j < 8; ++j)
            dacc += hs[kg * 8 + j] * bf2f((unsigned short)w8[j]);
        }
        sdec[tid] = dacc;
      }
      __syncthreads();

      float sd8[8];
#pragma unroll
      for (int j = 0; j < 8; ++j) sd8[j] = sdec[lane * 8 + j];
      for (int n = wvv; n < NN; n += 8) {
        const unsigned short* ep =
            enc_projb + ((size_t)b * NN + n) * 512 + lane * 8;
        bf16x8 v8 = *(const bf16x8*)ep;
        float a = 0.f;
#pragma unroll
        for (int j = 0; j < 8; ++j)
          a += tanh_fast(bf2f((unsigned short)v8[j]) + sd8[j]) * ew8[j];
#pragma unroll
        for (int off = 32; off; off >>= 1) a += __shfl_down(a, off, 64);
        if (lane == 0) sw[n] = a + eb0;
      }
      __syncthreads();

      float v = (tid < NN) ? sw[tid] : -1e30f;
      if (tid < 256) tmp[tid] = v;
      __syncthreads();
      for (int st = 128; st; st >>= 1) {
        if (tid < st) tmp[tid] = fmaxf(tmp[tid], tmp[tid + st]);
        __syncthreads();
      }
      float mx = tmp[0];
      __syncthreads();
      float e = (tid < NN) ? __expf(v - mx) : 0.f;
      if (tid < 256) tmp[tid] = e;
      __syncthreads();
      for (int st = 128; st; st >>= 1) {
        if (tid < st) tmp[tid] += tmp[tid + st];
        __syncthreads();
      }
      float inv = 1.f / tmp[0];
      if (tid < NN) sw[tid] = e * inv;
      __syncthreads();

      int half = tid >> 8, hp = tid & 255;
      const unsigned short* eo = encOutb + (size_t)b * NN * 512 + hp * 2;
      float a0 = 0.f, a1 = 0.f;
      int n0 = half * 98;
#pragma unroll 7
      for (int n = n0; n < n0 + 98; ++n) {
        float w = sw[n];
        unsigned u = *(const unsigned*)(eo + (size_t)n * 512);
        a0 += w * __uint_as_float((u & 0xffffu) << 16);
        a1 += w * __uint_as_float((u >> 16) << 16);
      }
      cp[half * 512 + hp * 2] = a0;
      cp[half * 512 + hp * 2 + 1] = a1;
      __syncthreads();
      xcur[(size_t)b * 1024 + 512 + tid] = f2bf(cp[tid] + cp[512 + tid]);
      __threadfence();
      __syncthreads();
      if (tid == 0)
        __hip_atomic_store(&fctx[b], s + 1, __ATOMIC_RELEASE,
                           __HIP_MEMORY_SCOPE_AGENT);
    }
  } else {
    // ======================= GATES CONSUMER =======================
    const int g = blockIdx.x - 64;
    const int nBase = g * 128;
    unsigned short* As = (unsigned short*)smem;            // 8 KB
    unsigned short* Bs = (unsigned short*)(smem + 8192);   // 16 KB
    float(*gbuf)[132] = (float(*)[132])(smem + 24576);     // 33.8 KB

    const int ar = tid >> 3, aq = tid & 7;
    const int sa = ldsw8(ar, aq);
    const int br0 = tid >> 3, bq0 = tid & 7;
    const int br1 = (tid + 512) >> 3, bq1 = tid & 7;
    const int sb0 = ldsw8(br0, bq0), sb1 = ldsw8(br1, bq1);

    const int lane = tid & 63;
    const int l15 = lane & 15;
    const int q = lane >> 4;
    const int wv = tid >> 6;
    const int wn = (wv & 3) * 32;

    for (int s = 0; s < 19; ++s) {
      unsigned short* xcur = xcat2 + (size_t)(s & 1) * 131072;
      unsigned short* xnxt = xcat2 + (size_t)((s + 1) & 1) * 131072;
      const float* gx = gates_all_ + (size_t)s * 131072;
      unsigned short* hb_slot = hb + (size_t)s * 32768;

      if (s > 0) {
        if (tid < 16) {
          while (__hip_atomic_load(&fh[tid], __ATOMIC_ACQUIRE,
                                   __HIP_MEMORY_SCOPE_AGENT) < s)
            __builtin_amdgcn_s_sleep(2);
        }
        __syncthreads();
      }

      floatx4 zero = {0.f, 0.f, 0.f, 0.f};
      floatx4 acc[4][2];
#pragma unroll
      for (int i = 0; i < 4; ++i)
#pragma unroll
        for (int j = 0; j < 2; ++j) acc[i][j] = zero;

#pragma unroll 1
      for (int ph = 0; ph < 2; ++ph) {
        if (ph == 1) {
          __syncthreads();
          if (tid < 64) {
            while (__hip_atomic_load(&fctx[tid], __ATOMIC_ACQUIRE,
                                     __HIP_MEMORY_SCOPE_AGENT) < s + 1)
              __builtin_amdgcn_s_sleep(2);
          }
          __syncthreads();
          __threadfence();
        }
        const int kLo = ph * 512;
#pragma unroll 1
        for (int k0 = kLo; k0 < kLo + 512; k0 += 64) {
          uint4 a0 = *(const uint4*)(xcur + (size_t)ar * 1024 + k0 + aq * 8);
          uint4 b0 = *(const uint4*)(Wgi + (size_t)(nBase + br0) * 1024 + k0 +
                                     bq0 * 8);
          uint4 b1 = *(const uint4*)(Wgi + (size_t)(nBase + br1) * 1024 + k0 +
                                     bq1 * 8);
          __syncthreads();
          *(uint4*)&As[sa] = a0;
          *(uint4*)&Bs[sb0] = b0;
          *(uint4*)&Bs[sb1] = b1;
          __syncthreads();
          if (tid < 256) {
#pragma unroll
            for (int ks = 0; ks < 2; ++ks) {
              bf16x8 af[4], bfv[2];
#pragma unroll
              for (int i = 0; i < 4; ++i)
                af[i] = *(const bf16x8*)&As[ldsw8(i * 16 + l15, ks * 4 + q)];
#pragma unroll
              for (int j = 0; j < 2; ++j)
                bfv[j] =
                    *(const bf16x8*)&Bs[ldsw8(wn + j * 16 + l15, ks * 4 + q)];
#pragma unroll
              for (int i = 0; i < 4; ++i)
#pragma unroll
                for (int j = 0; j < 2; ++j)
                  acc[i][j] = __builtin_amdgcn_mfma_f32_16x16x32_bf16(
                      af[i], bfv[j], acc[i][j], 0, 0, 0);
            }
          }
        }
      }

      if (tid < 256) {
#pragma unroll
        for (int i = 0; i < 4; ++i)
#pragma unroll
          for (int j = 0; j < 2; ++j)
#pragma unroll
            for (int p = 0; p < 4; ++p)
              gbuf[i * 16 + q * 4 + p][wn + j * 16 + l15] = acc[i][j][p];
      }
      __syncthreads();

#pragma unroll
      for (int it = 0; it < 4; ++it) {
        int e = it * 512 + tid;
        int bb = e >> 5, jl = e & 31;
        float4 gv = *(float4*)&gbuf[bb][jl * 4];
        float4 gxv = *(const float4*)(gx + (size_t)bb * 2048 + nBase + jl * 4);
        float ig = gv.x + gxv.x, fg = gv.y + gxv.y;
        float gg = gv.z + gxv.z, og = gv.w + gxv.w;
        int jg = (nBase >> 2) + jl;
        float cv = c[bb * 512 + jg];
        float cn = sigmoid_fast(fg) * cv + sigmoid_fast(ig) * tanh_fast(gg);
        float hn = sigmoid_fast(og) * tanh_fast(cn);
        c[bb * 512 + jg] = cn;
        unsigned short hbf = f2bf(hn);
        xnxt[(size_t)bb * 1024 + jg] = hbf;
        hb_slot[(size_t)bb * 512 + jg] = hbf;
      }
      __threadfence();
      __syncthreads();
      if (tid == 0)
        __hip_atomic_store(&fh[g], s + 1, __ATOMIC_RELEASE,
                           __HIP_MEMORY_SCOPE_AGENT);
    }
  }
}

// ---------------------------------------------------------------------------
// prep_all: ALL head work in one dispatch. Virtual-block grid-stride.
// ---------------------------------------------------------------------------
#define VB_ENCOUT 2512
#define VB_WGI    4080
#define VB_WB0I   4592
#define VB_ENCW   4848
#define VB_DECW   4912
#define VB_EMB    4976
#define VB_ZOUT   5136
#define VB_CZ     5449
#define VB_XCZ    5457
#define VB_HBPAD  5489
#define VB_BSUM   5493
#define VB_TOTAL  5494

struct PrepArgs {
  const float *fc_W, *enc_out, *W_ih, *W_hh, *b_ih, *b_hh, *enc_W, *dec_W, *emb;
  const int* captions;
  unsigned short *fcWb, *encOutb, *Wgi, *Wb0i, *encWb, *dec_Wp, *embxb, *hb,
      *xcat2;
  float *bsumi, *c, *out;
  int* flags;
};

__global__ __launch_bounds__(256) void prep_all(PrepArgs A) {
  const int tid = threadIdx.x;
  const uint4 z4 = {0u, 0u, 0u, 0u};
  for (int vb = blockIdx.x; vb < VB_TOTAL; vb += gridDim.x) {
    if (vb < VB_ENCOUT) {
      int base = vb * 4096;
#pragma unroll 4
      for (int i = 0; i < 16; ++i) {
        int idx = base + i * 256 + tid;
        int r = idx >> 9, cc = idx & 511;
        float v = (r < 20000) ? A.fc_W[(size_t)r * 512 + cc] : 0.f;
        A.fcWb[idx] = f2bf(v);
      }
    } else if (vb < VB_WGI) {
      int base = (vb - VB_ENCOUT) * 4096;
#pragma unroll 4
      for (int i = 0; i < 16; ++i) {
        int idx = base + i * 256 + tid;
        A.encOutb[idx] = f2bf(A.enc_out[idx]);
      }
    } else if (vb < VB_WB0I) {
      int base = (vb - VB_WGI) * 4096;
#pragma unroll 4
      for (int i = 0; i < 16; ++i) {
        int idx = base + i * 256 + tid;
        int np = idx >> 10, k = idx & 1023;
        int row = (np & 3) * 512 + (np >> 2);
        float v = (k < 512) ? A.W_hh[(size_t)row * 512 + k]
                            : A.W_ih[(size_t)row * 1024 + 512 + (k - 512)];
        A.Wgi[idx] = f2bf(v);
      }
    } else if (vb < VB_ENCW) {
      int base = (vb - VB_WB0I) * 4096;
#pragma unroll 4
      for (int i = 0; i < 16; ++i) {
        int idx = base + i * 256 + tid;
        int np = idx >> 9, k = idx & 511;
        int row = (np & 3) * 512 + (np >> 2);
        A.Wb0i[idx] = f2bf(A.W_ih[(size_t)row * 1024 + k]);
      }
    } else if (vb < VB_DECW) {
      int base = (vb - VB_ENCW) * 4096;
#pragma unroll 4
      for (int i = 0; i < 16; ++i) {
        int idx = base + i * 256 + tid;
        A.encWb[idx] = f2bf(A.enc_W[idx]);
      }
    } else if (vb < VB_EMB) {
      int base = (vb - VB_DECW) * 4096;
#pragma unroll 4
      for (int i = 0; i < 16; ++i) {
        int idx = base + i * 256 + tid;
        int kg = idx >> 12, rem = idx & 4095;
        int a = rem >> 3, j = rem & 7;
        A.dec_Wp[idx] = f2bf(A.dec_W[(size_t)a * 512 + kg * 8 + j]);
      }
    } else if (vb < VB_ZOUT) {
      int base = (vb - VB_EMB) * 4096;
#pragma unroll 4
      for (int i = 0; i < 16; ++i) {
        int idx = base + i * 256 + tid;
        int m = idx >> 9, cc = idx & 511;
        unsigned short r = 0;
        if (m < 1216) {
          int t = m >> 6, b = m & 63;
          int cap = A.captions[b * LL + t];
          r = f2bf(A.emb[(size_t)cap * 512 + cc]);
        }
        A.embxb[idx] = r;
      }
    } else if (vb < VB_CZ) {
      int u0 = (vb - VB_ZOUT) * 1024;
      floatx4 zf = {0.f, 0.f, 0.f, 0.f};
#pragma unroll
      for (int i = 0; i < 4; ++i) {
        int u = u0 + i * 256 + tid;
        if (u < 320000) {
          int b = u / 5000, v4 = u - b * 5000;
          *(floatx4*)(A.out + (size_t)b * ((size_t)LL * VV) + v4 * 4) = zf;
        }
      }
    } else if (vb < VB_XCZ) {
      int u0 = (vb - VB_CZ) * 1024;
      floatx4 zf = {0.f, 0.f, 0.f, 0.f};
#pragma unroll
      for (int i = 0; i < 4; ++i) {
        int u = u0 + i * 256 + tid;
        *(floatx4*)(A.c + (size_t)u * 4) = zf;
      }
    } else if (vb < VB_HBPAD) {
      int u0 = (vb - VB_XCZ) * 1024;
#pragma unroll
      for (int i = 0; i < 4; ++i) {
        int u = u0 + i * 256 + tid;
        ((uint4*)A.xcat2)[u] = z4;
      }
    } else if (vb < VB_BSUM) {
      int u0 = (vb - VB_HBPAD) * 1024;
      uint4* hp = (uint4*)(A.hb + (size_t)1216 * 512);
#pragma unroll
      for (int i = 0; i < 4; ++i) {
        int u = u0 + i * 256 + tid;
        hp[u] = z4;
      }
    } else {
#pragma unroll
      for (int i = 0; i < 8; ++i) {
        int e = i * 256 + tid;
        int row = (e & 3) * 512 + (e >> 2);
        A.bsumi[e] = A.b_ih[row] + A.b_hh[row];
        if (e < 80) A.flags[e] = 0;
      }
    }
  }
}

extern "C" void kernel_launch(void* const* d_in, const int* in_sizes, int n_in,
                              void* d_out, int out_size, void* d_ws, size_t ws_size,
                              hipStream_t stream) {
  const float* enc_out  = (const float*)d_in[0];
  const int*   captions = (const int*)d_in[1];
  const float* emb      = (const float*)d_in[2];
  const float* W_ih     = (const float*)d_in[3];
  const float* W_hh     = (const float*)d_in[4];
  const float* b_ih     = (const float*)d_in[5];
  const float* b_hh     = (const float*)d_in[6];
  const float* enc_W    = (const float*)d_in[7];
  const float* enc_b    = (const float*)d_in[8];
  const float* dec_W    = (const float*)d_in[9];
  const float* dec_b    = (const float*)d_in[10];
  const float* energy_W = (const float*)d_in[11];
  const float* energy_b = (const float*)d_in[12];
  const float* fc_W     = (const float*)d_in[13];
  const float* fc_b     = (const float*)d_in[14];
  float* out = (float*)d_out;

  // Workspace layout
  float* ws = (float*)d_ws;
  float* c          = ws;                                   // 64*512
  float* gates_all  = c + 32768;                            // 19*64*2048 (interleaved)
  float* bsumi      = gates_all + (size_t)19 * 131072;      // 2048
  int*   flags      = (int*)(bsumi + 2048);                 // 80
  unsigned short* enc_projb = (unsigned short*)(flags + 80);   // 12544*512
  unsigned short* fcWb    = enc_projb + (size_t)12544 * 512;   // 20096*512
  unsigned short* encWb   = fcWb + (size_t)20096 * 512;        // 512*512
  unsigned short* encOutb = encWb + (size_t)512 * 512;         // 12544*512
  unsigned short* Wb0i    = encOutb + (size_t)12544 * 512;     // 2048*512
  unsigned short* Wgi     = Wb0i + (size_t)2048 * 512;         // 2048*1024
  unsigned short* dec_Wp  = Wgi + (size_t)2048 * 1024;         // 512*512
  unsigned short* embxb   = dec_Wp + (size_t)512 * 512;        // 1280*512
  unsigned short* hb      = embxb + (size_t)1280 * 512;        // 1280*512
  unsigned short* xcat2   = hb + (size_t)1280 * 512;           // 2*128*1024

  PrepArgs pa;
  pa.fc_W = fc_W;     pa.enc_out = enc_out; pa.W_ih = W_ih;  pa.W_hh = W_hh;
  pa.b_ih = b_ih;     pa.b_hh = b_hh;       pa.enc_W = enc_W;
  pa.dec_W = dec_W;   pa.emb = emb;         pa.captions = captions;
  pa.fcWb = fcWb;     pa.encOutb = encOutb; pa.Wgi = Wgi;    pa.Wb0i = Wb0i;
  pa.encWb = encWb;   pa.dec_Wp = dec_Wp;   pa.embxb = embxb;
  pa.hb = hb;         pa.xcat2 = xcat2;     pa.bsumi = bsumi;
  pa.c = c;           pa.out = out;         pa.flags = flags;
  prep_all<<<2560, 256, 0, stream>>>(pa);

  // gates_x (interleaved) = embx @ Wb0i^T + bsumi   [MFMA]
  gemm_mfma_bt<<<dim3(16, 10), 256, 0, stream>>>(
      embxb, Wb0i, bsumi, gates_all, 1216, 2048, 512, 512, 2048, 0, 0);

  // enc_projb (bf16) = enc_out @ enc_W^T + enc_b   [MFMA, bf16 store]
  gemm_mfma_bt<<<dim3(4, 98), 256, 0, stream>>>(
      encOutb, encWb, enc_b, (float*)enc_projb, 12544, 512, 512, 512, 512, 2, 0);

  // Entire recurrent loop: ONE persistent dispatch (80 blocks, flag-synced).
  decoder_persist<<<80, 512, 0, stream>>>(
      enc_projb, encOutb, dec_Wp, dec_b, energy_W, energy_b, Wgi, gates_all,
      c, xcat2, hb, flags);

  // Batched logits: out[b, t+1, :] = h @ fc_W^T + fc_b  [MFMA, XCD-grouped]
  gemm_mfma_bt<<<1600, 256, 0, stream>>>(
      hb, fcWb, fc_b, out, 1216, 20000, 512, 512, 0, 1, 2);
}

// Round 12
// 1338.656 us; speedup vs baseline: 1.5043x; 1.5043x over previous
//
#include <hip/hip_runtime.h>
#include <hip/hip_bf16.h>
#include <math.h>

// Problem dims (fixed)
#define B   64
#define NN  196
#define HH  512
#define EE  512
#define AA  512
#define VV  20000
#define LL  20

typedef __attribute__((ext_vector_type(8))) short bf16x8;
typedef __attribute__((ext_vector_type(4))) float floatx4;

__device__ __forceinline__ float tanh_fast(float x) {
  float e2 = __expf(2.f * x);
  return 1.f - 2.f / (e2 + 1.f);
}
__device__ __forceinline__ float sigmoid_fast(float x) {
  return 1.f / (1.f + __expf(-x));
}
__device__ __forceinline__ float bf2f(unsigned short u) {
  return __uint_as_float(((unsigned)u) << 16);
}
__device__ __forceinline__ unsigned short f2bf(float v) {
  __hip_bfloat16 h = __float2bfloat16(v);
  return *reinterpret_cast<unsigned short*>(&h);
}

// RELAXED agent-scope atomics: lower to global_load/store with sc1 (coherent
// at device point, bypass non-coherent L2) and emit NO cache
// invalidate/writeback — unlike ACQUIRE/RELEASE, which invalidated L2 every
// step (round 11: FETCH 225 MB, 86 us/step, VALUBusy 6%).
__device__ __forceinline__ unsigned ald(const unsigned* p) {
  return __hip_atomic_load(p, __ATOMIC_RELAXED, __HIP_MEMORY_SCOPE_AGENT);
}
__device__ __forceinline__ void ast(unsigned* p, unsigned v) {
  __hip_atomic_store(p, v, __ATOMIC_RELAXED, __HIP_MEMORY_SCOPE_AGENT);
}
__device__ __forceinline__ int aldi(const int* p) {
  return __hip_atomic_load(p, __ATOMIC_RELAXED, __HIP_MEMORY_SCOPE_AGENT);
}
__device__ __forceinline__ void asti(int* p, int v) {
  __hip_atomic_store(p, v, __ATOMIC_RELAXED, __HIP_MEMORY_SCOPE_AGENT);
}

// Chunk-XOR LDS slot for BK=32 rows (4 x 16B chunks): c' = q4 ^ ((row>>1)&3).
// Measured (round 6): SQ_LDS_BANK_CONFLICT 6.4M -> 0 on the big GEMMs.
__device__ __forceinline__ int ldsw(int row, int q4) {
  return (row * 4 + (q4 ^ ((row >> 1) & 3))) * 8;
}
// Chunk-XOR for BK=64 rows (8 chunks). gates path only.
__device__ __forceinline__ int ldsw8(int row, int q8) {
  return (row * 8 + (q8 ^ (row & 7))) * 8;
}

// ---------------------------------------------------------------------------
// bf16 MFMA GEMM (EXACT round-6/9/10 version; measured: logits 88us, FETCH
// 24MB, 0 conflicts). 128x128 tile, BK=32, 256 thr. gridMX==2: XCD-grouped.
// outMode==0 fp32; ==1 logits scatter; ==2 bf16 store.
// ---------------------------------------------------------------------------
__global__ __launch_bounds__(256) void gemm_mfma_bt(
    const unsigned short* __restrict__ Xb, const unsigned short* __restrict__ Wb,
    const float* __restrict__ bias, float* __restrict__ C,
    int M, int N, int K, int lda, int ldC, int outMode, int gridMX) {
  __shared__ unsigned short As[128 * 32];
  __shared__ unsigned short Bs[128 * 32];
  const int tid = threadIdx.x;
  const int lane = tid & 63;
  const int l15 = lane & 15;
  const int q = lane >> 4;
  const int wv = tid >> 6;
  const int wm = (wv >> 1) * 64;
  const int wn = (wv & 1) * 64;
  int mBase, nBase;
  if (gridMX == 2) {
    const int MT = (M + 127) >> 7, NT = (N + 127) >> 7;
    int wg = blockIdx.x;
    int xcd = wg & 7, idx = wg >> 3;
    int kk = idx / MT, mi = idx - kk * MT;
    int p = kk * 8 + xcd;
    if (p >= NT) return;
    mBase = mi * 128;
    nBase = p * 128;
  } else {
    mBase = blockIdx.y * 128;
    nBase = blockIdx.x * 128;
  }

  const int c0 = tid, c1 = tid + 256;
  const int r0 = c0 >> 2, q0 = c0 & 3;
  const int r1 = c1 >> 2, q1 = c1 & 3;
  const int s0 = ldsw(r0, q0), s1 = ldsw(r1, q1);

  floatx4 zero = {0.f, 0.f, 0.f, 0.f};
  floatx4 acc[4][4];
#pragma unroll
  for (int i = 0; i < 4; ++i)
#pragma unroll
    for (int j = 0; j < 4; ++j) acc[i][j] = zero;

  for (int k0 = 0; k0 < K; k0 += 32) {
    uint4 a0 = *(const uint4*)(Xb + (size_t)(mBase + r0) * lda + k0 + q0 * 8);
    uint4 a1 = *(const uint4*)(Xb + (size_t)(mBase + r1) * lda + k0 + q1 * 8);
    uint4 b0 = *(const uint4*)(Wb + (size_t)(nBase + r0) * K + k0 + q0 * 8);
    uint4 b1 = *(const uint4*)(Wb + (size_t)(nBase + r1) * K + k0 + q1 * 8);
    __syncthreads();
    *(uint4*)&As[s0] = a0;
    *(uint4*)&As[s1] = a1;
    *(uint4*)&Bs[s0] = b0;
    *(uint4*)&Bs[s1] = b1;
    __syncthreads();
    bf16x8 af[4], bfv[4];
#pragma unroll
    for (int i = 0; i < 4; ++i)
      af[i] = *(const bf16x8*)&As[ldsw(wm + i * 16 + l15, q)];
#pragma unroll
    for (int j = 0; j < 4; ++j)
      bfv[j] = *(const bf16x8*)&Bs[ldsw(wn + j * 16 + l15, q)];
#pragma unroll
    for (int i = 0; i < 4; ++i)
#pragma unroll
      for (int j = 0; j < 4; ++j)
        acc[i][j] = __builtin_amdgcn_mfma_f32_16x16x32_bf16(af[i], bfv[j],
                                                            acc[i][j], 0, 0, 0);
  }

#pragma unroll
  for (int i = 0; i < 4; ++i) {
#pragma unroll
    for (int j = 0; j < 4; ++j) {
#pragma unroll
      for (int p = 0; p < 4; ++p) {
        int m = mBase + wm + i * 16 + q * 4 + p;
        int n = nBase + wn + j * 16 + l15;
        if (m < M && n < N) {
          float v = acc[i][j][p];
          if (bias) v += bias[n];
          if (outMode == 1) {
            size_t idx = (size_t)(m & 63) * ((size_t)LL * VV) +
                         (size_t)((m >> 6) + 1) * VV + n;
            C[idx] = v;
          } else if (outMode == 2) {
            ((unsigned short*)C)[(size_t)m * ldC + n] = f2bf(v);
          } else {
            C[(size_t)m * ldC + n] = v;
          }
        }
      }
    }
  }
}

// ---------------------------------------------------------------------------
// decoder_persist v2: ALL 19 steps, ONE dispatch, 80 blocks x 512 thr.
// ALL cross-block data (xcat2 halves) + flags use RELAXED agent atomics
// (coherent, no cache invalidation) -> weights/enc slices stay L2-warm for
// the whole kernel. Ordering: data stores -> s_waitcnt vmcnt(0) -> barrier ->
// flag store (data reaches coherence point before flag). Spins poll relaxed.
// Block-private data (c, dec_Wp, Wgi, enc_projb/encOutb slices, gx, hb) uses
// normal cached accesses.
// ---------------------------------------------------------------------------
__global__ __launch_bounds__(512) void decoder_persist(
    const unsigned short* __restrict__ enc_projb,
    const unsigned short* __restrict__ encOutb,
    const unsigned short* __restrict__ dec_Wp,  // [(k/8)*512+a] 8-chunk bf16
    const float* __restrict__ dec_b, const float* __restrict__ eW,
    const float* __restrict__ eb,
    const unsigned short* __restrict__ Wgi,     // [2048][1024] interleaved
    const float* __restrict__ gates_all_,       // [19][64][2048] interleaved
    float* __restrict__ c,
    unsigned short* __restrict__ xcat2,         // 2 x [128][1024] bf16
    unsigned short* __restrict__ hb,            // [1280][512] bf16
    int* __restrict__ flags) {                  // [0..63]=fctx, [64..79]=fh
  const int tid = threadIdx.x;
  __shared__ __align__(16) char smem[58368];
  int* fctx = flags;
  int* fh = flags + 64;

  if (blockIdx.x < 64) {
    // ======================= ATTENTION PRODUCER =======================
    const int b = blockIdx.x;
    float* hs = (float*)smem;              // 2048 B
    float* sdec = (float*)(smem + 2048);   // 2048 B
    float* sw = (float*)(smem + 4096);     // 1024 B (196 used)
    float* tmp = (float*)(smem + 5120);    // 1024 B
    float* cp = (float*)(smem + 6144);     // 4096 B
    const int wvv = tid >> 6, lane = tid & 63;
    float ew8[8];
#pragma unroll
    for (int j = 0; j < 8; ++j) ew8[j] = eW[lane * 8 + j];
    float eb0 = eb[0];
    float dbv = dec_b[tid];

    for (int s = 0; s < 19; ++s) {
      unsigned* xc32 = (unsigned*)(xcat2 + (size_t)(s & 1) * 131072);
      if (s > 0) {
        if (tid < 16) {
          while (aldi(&fh[tid]) < s) __builtin_amdgcn_s_sleep(1);
        }
        __syncthreads();
        // h (written by consumers) via coherent bypass loads
        if (tid < 256) {
          unsigned u = ald(xc32 + (b << 9) + tid);
          hs[2 * tid] = bf2f((unsigned short)(u & 0xffffu));
          hs[2 * tid + 1] = bf2f((unsigned short)(u >> 16));
        }
      } else {
        hs[tid] = 0.f;
      }
      __syncthreads();
      {
        float dacc = dbv;
#pragma unroll 4
        for (int kg = 0; kg < 64; ++kg) {
          bf16x8 w8 = *(const bf16x8*)(dec_Wp + (size_t)((kg << 9) + tid) * 8);
#pragma unroll
          for (int j = 0; j < 8; ++j)
            dacc += hs[kg * 8 + j] * bf2f((unsigned short)w8[j]);
        }
        sdec[tid] = dacc;
      }
      __syncthreads();

      float sd8[8];
#pragma unroll
      for (int j = 0; j < 8; ++j) sd8[j] = sdec[lane * 8 + j];
      for (int n = wvv; n < NN; n += 8) {
        const unsigned short* ep =
            enc_projb + ((size_t)b * NN + n) * 512 + lane * 8;
        bf16x8 v8 = *(const bf16x8*)ep;
        float a = 0.f;
#pragma unroll
        for (int j = 0; j < 8; ++j)
          a += tanh_fast(bf2f((unsigned short)v8[j]) + sd8[j]) * ew8[j];
#pragma unroll
        for (int off = 32; off; off >>= 1) a += __shfl_down(a, off, 64);
        if (lane == 0) sw[n] = a + eb0;
      }
      __syncthreads();

      float v = (tid < NN) ? sw[tid] : -1e30f;
      if (tid < 256) tmp[tid] = v;
      __syncthreads();
      for (int st = 128; st; st >>= 1) {
        if (tid < st) tmp[tid] = fmaxf(tmp[tid], tmp[tid + st]);
        __syncthreads();
      }
      float mx = tmp[0];
      __syncthreads();
      float e = (tid < NN) ? __expf(v - mx) : 0.f;
      if (tid < 256) tmp[tid] = e;
      __syncthreads();
      for (int st = 128; st; st >>= 1) {
        if (tid < st) tmp[tid] += tmp[tid + st];
        __syncthreads();
      }
      float inv = 1.f / tmp[0];
      if (tid < NN) sw[tid] = e * inv;
      __syncthreads();

      int half = tid >> 8, hp = tid & 255;
      const unsigned short* eo = encOutb + (size_t)b * NN * 512 + hp * 2;
      float a0 = 0.f, a1 = 0.f;
      int n0 = half * 98;
#pragma unroll 7
      for (int n = n0; n < n0 + 98; ++n) {
        float w = sw[n];
        unsigned u = *(const unsigned*)(eo + (size_t)n * 512);
        a0 += w * __uint_as_float((u & 0xffffu) << 16);
        a1 += w * __uint_as_float((u >> 16) << 16);
      }
      cp[half * 512 + hp * 2] = a0;
      cp[half * 512 + hp * 2 + 1] = a1;
      __syncthreads();
      // ctx -> bypass stores (u32-packed)
      if (tid < 256) {
        float v0 = cp[2 * tid] + cp[512 + 2 * tid];
        float v1 = cp[2 * tid + 1] + cp[512 + 2 * tid + 1];
        unsigned pk = (unsigned)f2bf(v0) | ((unsigned)f2bf(v1) << 16);
        ast(xc32 + (b << 9) + 256 + tid, pk);
      }
      asm volatile("s_waitcnt vmcnt(0)" ::: "memory");
      __syncthreads();
      if (tid == 0) asti(&fctx[b], s + 1);
    }
  } else {
    // ======================= GATES CONSUMER =======================
    const int g = blockIdx.x - 64;
    const int nBase = g * 128;
    unsigned short* As = (unsigned short*)smem;            // 8 KB
    unsigned short* Bs = (unsigned short*)(smem + 8192);   // 16 KB
    float(*gbuf)[132] = (float(*)[132])(smem + 24576);     // 33.8 KB

    const int ar = tid >> 3, aq = tid & 7;
    const int sa = ldsw8(ar, aq);
    const int br0 = tid >> 3, bq0 = tid & 7;
    const int br1 = (tid + 512) >> 3, bq1 = tid & 7;
    const int sb0 = ldsw8(br0, bq0), sb1 = ldsw8(br1, bq1);

    const int lane = tid & 63;
    const int l15 = lane & 15;
    const int q = lane >> 4;
    const int wv = tid >> 6;
    const int wn = (wv & 3) * 32;

    for (int s = 0; s < 19; ++s) {
      unsigned* xc32 = (unsigned*)(xcat2 + (size_t)(s & 1) * 131072);
      unsigned* xn32 = (unsigned*)(xcat2 + (size_t)((s + 1) & 1) * 131072);
      const float* gx = gates_all_ + (size_t)s * 131072;
      unsigned* hb32 = (unsigned*)(hb + (size_t)s * 32768);

      if (s > 0) {
        if (tid < 16) {
          while (aldi(&fh[tid]) < s) __builtin_amdgcn_s_sleep(1);
        }
        __syncthreads();
      }

      floatx4 zero = {0.f, 0.f, 0.f, 0.f};
      floatx4 acc[4][2];
#pragma unroll
      for (int i = 0; i < 4; ++i)
#pragma unroll
        for (int j = 0; j < 2; ++j) acc[i][j] = zero;

#pragma unroll 1
      for (int ph = 0; ph < 2; ++ph) {
        if (ph == 1) {
          __syncthreads();
          if (tid < 64) {
            while (aldi(&fctx[tid]) < s + 1) __builtin_amdgcn_s_sleep(1);
          }
          __syncthreads();
        }
        const int kLo = ph * 512;
#pragma unroll 1
        for (int k0 = kLo; k0 < kLo + 512; k0 += 64) {
          // A (xcat, cross-block data) via coherent bypass loads
          const unsigned* ap = xc32 + (ar << 9) + (k0 >> 1) + aq * 4;
          unsigned au0 = ald(ap + 0);
          unsigned au1 = ald(ap + 1);
          unsigned au2 = ald(ap + 2);
          unsigned au3 = ald(ap + 3);
          // B (weights, block-private) via normal cached loads
          uint4 b0 = *(const uint4*)(Wgi + (size_t)(nBase + br0) * 1024 + k0 +
                                     bq0 * 8);
          uint4 b1 = *(const uint4*)(Wgi + (size_t)(nBase + br1) * 1024 + k0 +
                                     bq1 * 8);
          __syncthreads();
          {
            uint4 av;
            av.x = au0; av.y = au1; av.z = au2; av.w = au3;
            *(uint4*)&As[sa] = av;
          }
          *(uint4*)&Bs[sb0] = b0;
          *(uint4*)&Bs[sb1] = b1;
          __syncthreads();
          if (tid < 256) {
#pragma unroll
            for (int ks = 0; ks < 2; ++ks) {
              bf16x8 af[4], bfv[2];
#pragma unroll
              for (int i = 0; i < 4; ++i)
                af[i] = *(const bf16x8*)&As[ldsw8(i * 16 + l15, ks * 4 + q)];
#pragma unroll
              for (int j = 0; j < 2; ++j)
                bfv[j] =
                    *(const bf16x8*)&Bs[ldsw8(wn + j * 16 + l15, ks * 4 + q)];
#pragma unroll
              for (int i = 0; i < 4; ++i)
#pragma unroll
                for (int j = 0; j < 2; ++j)
                  acc[i][j] = __builtin_amdgcn_mfma_f32_16x16x32_bf16(
                      af[i], bfv[j], acc[i][j], 0, 0, 0);
            }
          }
        }
      }

      if (tid < 256) {
#pragma unroll
        for (int i = 0; i < 4; ++i)
#pragma unroll
          for (int j = 0; j < 2; ++j)
#pragma unroll
            for (int p = 0; p < 4; ++p)
              gbuf[i * 16 + q * 4 + p][wn + j * 16 + l15] = acc[i][j][p];
      }
      __syncthreads();

      // Pointwise: 1024 pairs (b, jp), 2 per thread; pack u32.
#pragma unroll
      for (int it = 0; it < 2; ++it) {
        int p = it * 512 + tid;
        int bb = p >> 4, jp = p & 15;
        float4 gv0 = *(float4*)&gbuf[bb][jp * 8];
        float4 gv1 = *(float4*)&gbuf[bb][jp * 8 + 4];
        const float* gxp = gx + (size_t)bb * 2048 + nBase + jp * 8;
        float4 gx0 = *(const float4*)(gxp);
        float4 gx1 = *(const float4*)(gxp + 4);
        int jg0 = (nBase >> 2) + jp * 2;
        float cv0 = c[bb * 512 + jg0];
        float cv1 = c[bb * 512 + jg0 + 1];
        float cn0 = sigmoid_fast(gv0.y + gx0.y) * cv0 +
                    sigmoid_fast(gv0.x + gx0.x) * tanh_fast(gv0.z + gx0.z);
        float hn0 = sigmoid_fast(gv0.w + gx0.w) * tanh_fast(cn0);
        float cn1 = sigmoid_fast(gv1.y + gx1.y) * cv1 +
                    sigmoid_fast(gv1.x + gx1.x) * tanh_fast(gv1.z + gx1.z);
        float hn1 = sigmoid_fast(gv1.w + gx1.w) * tanh_fast(cn1);
        c[bb * 512 + jg0] = cn0;
        c[bb * 512 + jg0 + 1] = cn1;
        unsigned pk = (unsigned)f2bf(hn0) | ((unsigned)f2bf(hn1) << 16);
        ast(xn32 + ((bb << 10) + jg0) / 2, pk);       // h -> next xcat (bypass)
        hb32[((bb << 9) + jg0) / 2] = pk;             // history (cached)
      }
      asm volatile("s_waitcnt vmcnt(0)" ::: "memory");
      __syncthreads();
      if (tid == 0) asti(&fh[g], s + 1);
    }
  }
}

// ---------------------------------------------------------------------------
// prep_all: ALL head work in one dispatch. Virtual-block grid-stride.
// ---------------------------------------------------------------------------
#define VB_ENCOUT 2512
#define VB_WGI    4080
#define VB_WB0I   4592
#define VB_ENCW   4848
#define VB_DECW   4912
#define VB_EMB    4976
#define VB_ZOUT   5136
#define VB_CZ     5449
#define VB_XCZ    5457
#define VB_HBPAD  5489
#define VB_BSUM   5493
#define VB_TOTAL  5494

struct PrepArgs {
  const float *fc_W, *enc_out, *W_ih, *W_hh, *b_ih, *b_hh, *enc_W, *dec_W, *emb;
  const int* captions;
  unsigned short *fcWb, *encOutb, *Wgi, *Wb0i, *encWb, *dec_Wp, *embxb, *hb,
      *xcat2;
  float *bsumi, *c, *out;
  int* flags;
};

__global__ __launch_bounds__(256) void prep_all(PrepArgs A) {
  const int tid = threadIdx.x;
  const uint4 z4 = {0u, 0u, 0u, 0u};
  for (int vb = blockIdx.x; vb < VB_TOTAL; vb += gridDim.x) {
    if (vb < VB_ENCOUT) {
      int base = vb * 4096;
#pragma unroll 4
      for (int i = 0; i < 16; ++i) {
        int idx = base + i * 256 + tid;
        int r = idx >> 9, cc = idx & 511;
        float v = (r < 20000) ? A.fc_W[(size_t)r * 512 + cc] : 0.f;
        A.fcWb[idx] = f2bf(v);
      }
    } else if (vb < VB_WGI) {
      int base = (vb - VB_ENCOUT) * 4096;
#pragma unroll 4
      for (int i = 0; i < 16; ++i) {
        int idx = base + i * 256 + tid;
        A.encOutb[idx] = f2bf(A.enc_out[idx]);
      }
    } else if (vb < VB_WB0I) {
      int base = (vb - VB_WGI) * 4096;
#pragma unroll 4
      for (int i = 0; i < 16; ++i) {
        int idx = base + i * 256 + tid;
        int np = idx >> 10, k = idx & 1023;
        int row = (np & 3) * 512 + (np >> 2);
        float v = (k < 512) ? A.W_hh[(size_t)row * 512 + k]
                            : A.W_ih[(size_t)row * 1024 + 512 + (k - 512)];
        A.Wgi[idx] = f2bf(v);
      }
    } else if (vb < VB_ENCW) {
      int base = (vb - VB_WB0I) * 4096;
#pragma unroll 4
      for (int i = 0; i < 16; ++i) {
        int idx = base + i * 256 + tid;
        int np = idx >> 9, k = idx & 511;
        int row = (np & 3) * 512 + (np >> 2);
        A.Wb0i[idx] = f2bf(A.W_ih[(size_t)row * 1024 + k]);
      }
    } else if (vb < VB_DECW) {
      int base = (vb - VB_ENCW) * 4096;
#pragma unroll 4
      for (int i = 0; i < 16; ++i) {
        int idx = base + i * 256 + tid;
        A.encWb[idx] = f2bf(A.enc_W[idx]);
      }
    } else if (vb < VB_EMB) {
      int base = (vb - VB_DECW) * 4096;
#pragma unroll 4
      for (int i = 0; i < 16; ++i) {
        int idx = base + i * 256 + tid;
        int kg = idx >> 12, rem = idx & 4095;
        int a = rem >> 3, j = rem & 7;
        A.dec_Wp[idx] = f2bf(A.dec_W[(size_t)a * 512 + kg * 8 + j]);
      }
    } else if (vb < VB_ZOUT) {
      int base = (vb - VB_EMB) * 4096;
#pragma unroll 4
      for (int i = 0; i < 16; ++i) {
        int idx = base + i * 256 + tid;
        int m = idx >> 9, cc = idx & 511;
        unsigned short r = 0;
        if (m < 1216) {
          int t = m >> 6, b = m & 63;
          int cap = A.captions[b * LL + t];
          r = f2bf(A.emb[(size_t)cap * 512 + cc]);
        }
        A.embxb[idx] = r;
      }
    } else if (vb < VB_CZ) {
      int u0 = (vb - VB_ZOUT) * 1024;
      floatx4 zf = {0.f, 0.f, 0.f, 0.f};
#pragma unroll
      for (int i = 0; i < 4; ++i) {
        int u = u0 + i * 256 + tid;
        if (u < 320000) {
          int b = u / 5000, v4 = u - b * 5000;
          *(floatx4*)(A.out + (size_t)b * ((size_t)LL * VV) + v4 * 4) = zf;
        }
      }
    } else if (vb < VB_XCZ) {
      int u0 = (vb - VB_CZ) * 1024;
      floatx4 zf = {0.f, 0.f, 0.f, 0.f};
#pragma unroll
      for (int i = 0; i < 4; ++i) {
        int u = u0 + i * 256 + tid;
        *(floatx4*)(A.c + (size_t)u * 4) = zf;
      }
    } else if (vb < VB_HBPAD) {
      int u0 = (vb - VB_XCZ) * 1024;
#pragma unroll
      for (int i = 0; i < 4; ++i) {
        int u = u0 + i * 256 + tid;
        ((uint4*)A.xcat2)[u] = z4;
      }
    } else if (vb < VB_BSUM) {
      int u0 = (vb - VB_HBPAD) * 1024;
      uint4* hp = (uint4*)(A.hb + (size_t)1216 * 512);
#pragma unroll
      for (int i = 0; i < 4; ++i) {
        int u = u0 + i * 256 + tid;
        hp[u] = z4;
      }
    } else {
#pragma unroll
      for (int i = 0; i < 8; ++i) {
        int e = i * 256 + tid;
        int row = (e & 3) * 512 + (e >> 2);
        A.bsumi[e] = A.b_ih[row] + A.b_hh[row];
        if (e < 80) A.flags[e] = 0;
      }
    }
  }
}

extern "C" void kernel_launch(void* const* d_in, const int* in_sizes, int n_in,
                              void* d_out, int out_size, void* d_ws, size_t ws_size,
                              hipStream_t stream) {
  const float* enc_out  = (const float*)d_in[0];
  const int*   captions = (const int*)d_in[1];
  const float* emb      = (const float*)d_in[2];
  const float* W_ih     = (const float*)d_in[3];
  const float* W_hh     = (const float*)d_in[4];
  const float* b_ih     = (const float*)d_in[5];
  const float* b_hh     = (const float*)d_in[6];
  const float* enc_W    = (const float*)d_in[7];
  const float* enc_b    = (const float*)d_in[8];
  const float* dec_W    = (const float*)d_in[9];
  const float* dec_b    = (const float*)d_in[10];
  const float* energy_W = (const float*)d_in[11];
  const float* energy_b = (const float*)d_in[12];
  const float* fc_W     = (const float*)d_in[13];
  const float* fc_b     = (const float*)d_in[14];
  float* out = (float*)d_out;

  // Workspace layout
  float* ws = (float*)d_ws;
  float* c          = ws;                                   // 64*512
  float* gates_all  = c + 32768;                            // 19*64*2048 (interleaved)
  float* bsumi      = gates_all + (size_t)19 * 131072;      // 2048
  int*   flags      = (int*)(bsumi + 2048);                 // 80
  unsigned short* enc_projb = (unsigned short*)(flags + 80);   // 12544*512
  unsigned short* fcWb    = enc_projb + (size_t)12544 * 512;   // 20096*512
  unsigned short* encWb   = fcWb + (size_t)20096 * 512;        // 512*512
  unsigned short* encOutb = encWb + (size_t)512 * 512;         // 12544*512
  unsigned short* Wb0i    = encOutb + (size_t)12544 * 512;     // 2048*512
  unsigned short* Wgi     = Wb0i + (size_t)2048 * 512;         // 2048*1024
  unsigned short* dec_Wp  = Wgi + (size_t)2048 * 1024;         // 512*512
  unsigned short* embxb   = dec_Wp + (size_t)512 * 512;        // 1280*512
  unsigned short* hb      = embxb + (size_t)1280 * 512;        // 1280*512
  unsigned short* xcat2   = hb + (size_t)1280 * 512;           // 2*128*1024

  PrepArgs pa;
  pa.fc_W = fc_W;     pa.enc_out = enc_out; pa.W_ih = W_ih;  pa.W_hh = W_hh;
  pa.b_ih = b_ih;     pa.b_hh = b_hh;       pa.enc_W = enc_W;
  pa.dec_W = dec_W;   pa.emb = emb;         pa.captions = captions;
  pa.fcWb = fcWb;     pa.encOutb = encOutb; pa.Wgi = Wgi;    pa.Wb0i = Wb0i;
  pa.encWb = encWb;   pa.dec_Wp = dec_Wp;   pa.embxb = embxb;
  pa.hb = hb;         pa.xcat2 = xcat2;     pa.bsumi = bsumi;
  pa.c = c;           pa.out = out;         pa.flags = flags;
  prep_all<<<2560, 256, 0, stream>>>(pa);

  // gates_x (interleaved) = embx @ Wb0i^T + bsumi   [MFMA]
  gemm_mfma_bt<<<dim3(16, 10), 256, 0, stream>>>(
      embxb, Wb0i, bsumi, gates_all, 1216, 2048, 512, 512, 2048, 0, 0);

  // enc_projb (bf16) = enc_out @ enc_W^T + enc_b   [MFMA, bf16 store]
  gemm_mfma_bt<<<dim3(4, 98), 256, 0, stream>>>(
      encOutb, encWb, enc_b, (float*)enc_projb, 12544, 512, 512, 512, 512, 2, 0);

  // Entire recurrent loop: ONE persistent dispatch (80 blocks, relaxed-flag
  // synced, caches never invalidated).
  decoder_persist<<<80, 512, 0, stream>>>(
      enc_projb, encOutb, dec_Wp, dec_b, energy_W, energy_b, Wgi, gates_all,
      c, xcat2, hb, flags);

  // Batched logits: out[b, t+1, :] = h @ fc_W^T + fc_b  [MFMA, XCD-grouped]
  gemm_mfma_bt<<<1600, 256, 0, stream>>>(
      hb, fcWb, fc_b, out, 1216, 20000, 512, 512, 0, 1, 2);
}

// Round 13
// 1334.170 us; speedup vs baseline: 1.5093x; 1.0034x over previous
//
#include <hip/hip_runtime.h>
#include <hip/hip_bf16.h>
#include <math.h>

// Problem dims (fixed)
#define B   64
#define NN  196
#define HH  512
#define EE  512
#define AA  512
#define VV  20000
#define LL  20

typedef __attribute__((ext_vector_type(8))) short bf16x8;
typedef __attribute__((ext_vector_type(4))) float floatx4;

__device__ __forceinline__ float tanh_fast(float x) {
  float e2 = __expf(2.f * x);
  return 1.f - 2.f / (e2 + 1.f);
}
__device__ __forceinline__ float sigmoid_fast(float x) {
  return 1.f / (1.f + __expf(-x));
}
__device__ __forceinline__ float bf2f(unsigned short u) {
  return __uint_as_float(((unsigned)u) << 16);
}
__device__ __forceinline__ unsigned short f2bf(float v) {
  __hip_bfloat16 h = __float2bfloat16(v);
  return *reinterpret_cast<unsigned short*>(&h);
}

// RELAXED agent-scope atomics: coherent, NO cache invalidate/writeback.
// (Round 12 proven: acquire/release invalidates cost 660 us over the loop.)
__device__ __forceinline__ unsigned ald(const unsigned* p) {
  return __hip_atomic_load(p, __ATOMIC_RELAXED, __HIP_MEMORY_SCOPE_AGENT);
}
__device__ __forceinline__ void ast(unsigned* p, unsigned v) {
  __hip_atomic_store(p, v, __ATOMIC_RELAXED, __HIP_MEMORY_SCOPE_AGENT);
}
__device__ __forceinline__ int aldi(const int* p) {
  return __hip_atomic_load(p, __ATOMIC_RELAXED, __HIP_MEMORY_SCOPE_AGENT);
}
__device__ __forceinline__ void asti(int* p, int v) {
  __hip_atomic_store(p, v, __ATOMIC_RELAXED, __HIP_MEMORY_SCOPE_AGENT);
}

// Chunk-XOR LDS slot for BK=32 rows (4 x 16B chunks). Measured: 0 conflicts.
__device__ __forceinline__ int ldsw(int row, int q4) {
  return (row * 4 + (q4 ^ ((row >> 1) & 3))) * 8;
}
// Chunk-XOR for BK=64 rows (8 chunks). gates path only.
__device__ __forceinline__ int ldsw8(int row, int q8) {
  return (row * 8 + (q8 ^ (row & 7))) * 8;
}

// ---------------------------------------------------------------------------
// bf16 MFMA GEMM (EXACT round-6/9/10 version; measured: logits 88us, FETCH
// 24MB, 0 conflicts). 128x128 tile, BK=32, 256 thr. gridMX==2: XCD-grouped.
// ---------------------------------------------------------------------------
__global__ __launch_bounds__(256) void gemm_mfma_bt(
    const unsigned short* __restrict__ Xb, const unsigned short* __restrict__ Wb,
    const float* __restrict__ bias, float* __restrict__ C,
    int M, int N, int K, int lda, int ldC, int outMode, int gridMX) {
  __shared__ unsigned short As[128 * 32];
  __shared__ unsigned short Bs[128 * 32];
  const int tid = threadIdx.x;
  const int lane = tid & 63;
  const int l15 = lane & 15;
  const int q = lane >> 4;
  const int wv = tid >> 6;
  const int wm = (wv >> 1) * 64;
  const int wn = (wv & 1) * 64;
  int mBase, nBase;
  if (gridMX == 2) {
    const int MT = (M + 127) >> 7, NT = (N + 127) >> 7;
    int wg = blockIdx.x;
    int xcd = wg & 7, idx = wg >> 3;
    int kk = idx / MT, mi = idx - kk * MT;
    int p = kk * 8 + xcd;
    if (p >= NT) return;
    mBase = mi * 128;
    nBase = p * 128;
  } else {
    mBase = blockIdx.y * 128;
    nBase = blockIdx.x * 128;
  }

  const int c0 = tid, c1 = tid + 256;
  const int r0 = c0 >> 2, q0 = c0 & 3;
  const int r1 = c1 >> 2, q1 = c1 & 3;
  const int s0 = ldsw(r0, q0), s1 = ldsw(r1, q1);

  floatx4 zero = {0.f, 0.f, 0.f, 0.f};
  floatx4 acc[4][4];
#pragma unroll
  for (int i = 0; i < 4; ++i)
#pragma unroll
    for (int j = 0; j < 4; ++j) acc[i][j] = zero;

  for (int k0 = 0; k0 < K; k0 += 32) {
    uint4 a0 = *(const uint4*)(Xb + (size_t)(mBase + r0) * lda + k0 + q0 * 8);
    uint4 a1 = *(const uint4*)(Xb + (size_t)(mBase + r1) * lda + k0 + q1 * 8);
    uint4 b0 = *(const uint4*)(Wb + (size_t)(nBase + r0) * K + k0 + q0 * 8);
    uint4 b1 = *(const uint4*)(Wb + (size_t)(nBase + r1) * K + k0 + q1 * 8);
    __syncthreads();
    *(uint4*)&As[s0] = a0;
    *(uint4*)&As[s1] = a1;
    *(uint4*)&Bs[s0] = b0;
    *(uint4*)&Bs[s1] = b1;
    __syncthreads();
    bf16x8 af[4], bfv[4];
#pragma unroll
    for (int i = 0; i < 4; ++i)
      af[i] = *(const bf16x8*)&As[ldsw(wm + i * 16 + l15, q)];
#pragma unroll
    for (int j = 0; j < 4; ++j)
      bfv[j] = *(const bf16x8*)&Bs[ldsw(wn + j * 16 + l15, q)];
#pragma unroll
    for (int i = 0; i < 4; ++i)
#pragma unroll
      for (int j = 0; j < 4; ++j)
        acc[i][j] = __builtin_amdgcn_mfma_f32_16x16x32_bf16(af[i], bfv[j],
                                                            acc[i][j], 0, 0, 0);
  }

#pragma unroll
  for (int i = 0; i < 4; ++i) {
#pragma unroll
    for (int j = 0; j < 4; ++j) {
#pragma unroll
      for (int p = 0; p < 4; ++p) {
        int m = mBase + wm + i * 16 + q * 4 + p;
        int n = nBase + wn + j * 16 + l15;
        if (m < M && n < N) {
          float v = acc[i][j][p];
          if (bias) v += bias[n];
          if (outMode == 1) {
            size_t idx = (size_t)(m & 63) * ((size_t)LL * VV) +
                         (size_t)((m >> 6) + 1) * VV + n;
            C[idx] = v;
          } else if (outMode == 2) {
            ((unsigned short*)C)[(size_t)m * ldC + n] = f2bf(v);
          } else {
            C[(size_t)m * ldC + n] = v;
          }
        }
      }
    }
  }
}

// ---------------------------------------------------------------------------
// decoder_persist v3: ALL 19 steps, ONE dispatch, 80 blocks x 512 thr.
// Relaxed-atomic flag/data protocol (round 12, proven). New vs v2:
//  - 128 of 196 enc_projb rows persisted in LDS (128 KB, loaded once) ->
//    per-XCD L2 working set drops below 4 MB -> encOutb/dec_Wp/proj-tail
//    L2-warm across steps (round 12: 12 MB/step refetch, thrash).
//  - ctx loop: 16B/lane loads (8 n-stripes x 64 col-groups + LDS reduce)
//    with 1-deep prefetch (was 4B/lane, 1 load in flight).
//  - scores streamed rows: 1-deep prefetch.  - dec matvec skipped at s=0.
// LDS: 150 KB static (precedent: m201 8-phase uses 128 KB static).
// ---------------------------------------------------------------------------
__global__ __launch_bounds__(512) void decoder_persist(
    const unsigned short* __restrict__ enc_projb,
    const unsigned short* __restrict__ encOutb,
    const unsigned short* __restrict__ dec_Wp,  // [(k/8)*512+a] 8-chunk bf16
    const float* __restrict__ dec_b, const float* __restrict__ eW,
    const float* __restrict__ eb,
    const unsigned short* __restrict__ Wgi,     // [2048][1024] interleaved
    const float* __restrict__ gates_all_,       // [19][64][2048] interleaved
    float* __restrict__ c,
    unsigned short* __restrict__ xcat2,         // 2 x [128][1024] bf16
    unsigned short* __restrict__ hb,            // [1280][512] bf16
    int* __restrict__ flags) {                  // [0..63]=fctx, [64..79]=fh
  const int tid = threadIdx.x;
  __shared__ __align__(16) char smem[153600];
  int* fctx = flags;
  int* fh = flags + 64;

  if (blockIdx.x < 64) {
    // ======================= ATTENTION PRODUCER =======================
    const int b = blockIdx.x;
    unsigned short* projL = (unsigned short*)smem;  // 128 rows x 1KB = 131072
    float* hs = (float*)(smem + 131072);            // 2048
    float* sdec = (float*)(smem + 133120);          // 2048
    float* sw = (float*)(smem + 135168);            // 1024 (196 used)
    float* tmp = (float*)(smem + 136192);           // 1024
    float* cpR = (float*)(smem + 137216);           // 8*512*4 = 16384
    const int wvv = tid >> 6, lane = tid & 63;
    float ew8[8];
#pragma unroll
    for (int j = 0; j < 8; ++j) ew8[j] = eW[lane * 8 + j];
    float eb0 = eb[0];
    float dbv = dec_b[tid];

    // Persist enc_projb rows [0,128) in LDS once (reused all 19 steps)
    {
      const uint4* src = (const uint4*)(enc_projb + (size_t)b * NN * 512);
      uint4* dst = (uint4*)projL;
      for (int i = tid; i < 128 * 64; i += 512) dst[i] = src[i];
    }

    for (int s = 0; s < 19; ++s) {
      unsigned* xc32 = (unsigned*)(xcat2 + (size_t)(s & 1) * 131072);
      if (s > 0) {
        if (tid < 16) {
          while (aldi(&fh[tid]) < s) __builtin_amdgcn_s_sleep(1);
        }
        __syncthreads();
        // h (written by consumers) via coherent bypass loads
        if (tid < 256) {
          unsigned u = ald(xc32 + (b << 9) + tid);
          hs[2 * tid] = bf2f((unsigned short)(u & 0xffffu));
          hs[2 * tid + 1] = bf2f((unsigned short)(u >> 16));
        }
        __syncthreads();
        float dacc = dbv;
#pragma unroll 4
        for (int kg = 0; kg < 64; ++kg) {
          bf16x8 w8 = *(const bf16x8*)(dec_Wp + (size_t)((kg << 9) + tid) * 8);
#pragma unroll
          for (int j = 0; j < 8; ++j)
            dacc += hs[kg * 8 + j] * bf2f((unsigned short)w8[j]);
        }
        sdec[tid] = dacc;
      } else {
        sdec[tid] = dbv;  // h_0 = 0
      }
      __syncthreads();

      float sd8[8];
#pragma unroll
      for (int j = 0; j < 8; ++j) sd8[j] = sdec[lane * 8 + j];
      // scores: LDS-resident rows [0,128)
      for (int n = wvv; n < 128; n += 8) {
        bf16x8 v8 = *(const bf16x8*)&projL[n * 512 + lane * 8];
        float a = 0.f;
#pragma unroll
        for (int j = 0; j < 8; ++j)
          a += tanh_fast(bf2f((unsigned short)v8[j]) + sd8[j]) * ew8[j];
#pragma unroll
        for (int off = 32; off; off >>= 1) a += __shfl_down(a, off, 64);
        if (lane == 0) sw[n] = a + eb0;
      }
      // scores: streamed rows [128,196) with 1-deep prefetch (L2-warm)
      {
        const unsigned short* epb =
            enc_projb + (size_t)b * NN * 512 + lane * 8;
        int n = 128 + wvv;
        bf16x8 v8 = *(const bf16x8*)(epb + (size_t)n * 512);
#pragma unroll 1
        while (true) {
          int n2 = n + 8;
          bf16x8 vnx = v8;
          if (n2 < NN) vnx = *(const bf16x8*)(epb + (size_t)n2 * 512);
          float a = 0.f;
#pragma unroll
          for (int j = 0; j < 8; ++j)
            a += tanh_fast(bf2f((unsigned short)v8[j]) + sd8[j]) * ew8[j];
#pragma unroll
          for (int off = 32; off; off >>= 1) a += __shfl_down(a, off, 64);
          if (lane == 0) sw[n] = a + eb0;
          v8 = vnx;
          n = n2;
          if (n >= NN) break;
        }
      }
      __syncthreads();

      // softmax over N
      float v = (tid < NN) ? sw[tid] : -1e30f;
      if (tid < 256) tmp[tid] = v;
      __syncthreads();
      for (int st = 128; st; st >>= 1) {
        if (tid < st) tmp[tid] = fmaxf(tmp[tid], tmp[tid + st]);
        __syncthreads();
      }
      float mx = tmp[0];
      __syncthreads();
      float e = (tid < NN) ? __expf(v - mx) : 0.f;
      if (tid < 256) tmp[tid] = e;
      __syncthreads();
      for (int st = 128; st; st >>= 1) {
        if (tid < st) tmp[tid] += tmp[tid + st];
        __syncthreads();
      }
      float inv = 1.f / tmp[0];
      if (tid < NN) sw[tid] = e * inv;
      __syncthreads();

      // ctx: 8 n-stripes x 64 col-groups, 16B/lane loads, 1-deep prefetch
      {
        const int st = tid >> 6;   // n-stripe (uniform per wave)
        const int cg = tid & 63;   // col group: cols cg*8 .. cg*8+7
        float a[8] = {0.f, 0.f, 0.f, 0.f, 0.f, 0.f, 0.f, 0.f};
        const unsigned short* eo =
            encOutb + (size_t)b * NN * 512 + cg * 8;
        int n = st;
        bf16x8 v8 = *(const bf16x8*)(eo + (size_t)n * 512);
#pragma unroll 1
        while (true) {
          int n2 = n + 8;
          bf16x8 vnx = v8;
          if (n2 < NN) vnx = *(const bf16x8*)(eo + (size_t)n2 * 512);
          float w = sw[n];
#pragma unroll
          for (int j = 0; j < 8; ++j)
            a[j] += w * bf2f((unsigned short)v8[j]);
          v8 = vnx;
          n = n2;
          if (n >= NN) break;
        }
        floatx4 a0v = {a[0], a[1], a[2], a[3]};
        floatx4 a1v = {a[4], a[5], a[6], a[7]};
        *(floatx4*)&cpR[st * 512 + cg * 8] = a0v;
        *(floatx4*)&cpR[st * 512 + cg * 8 + 4] = a1v;
      }
      __syncthreads();
      if (tid < 256) {
        float v0 = 0.f, v1 = 0.f;
#pragma unroll
        for (int st = 0; st < 8; ++st) {
          v0 += cpR[st * 512 + 2 * tid];
          v1 += cpR[st * 512 + 2 * tid + 1];
        }
        unsigned pk = (unsigned)f2bf(v0) | ((unsigned)f2bf(v1) << 16);
        ast(xc32 + (b << 9) + 256 + tid, pk);
      }
      asm volatile("s_waitcnt vmcnt(0)" ::: "memory");
      __syncthreads();
      if (tid == 0) asti(&fctx[b], s + 1);
    }
  } else {
    // ======================= GATES CONSUMER =======================
    const int g = blockIdx.x - 64;
    const int nBase = g * 128;
    unsigned short* As = (unsigned short*)smem;            // 8 KB
    unsigned short* Bs = (unsigned short*)(smem + 8192);   // 16 KB
    float(*gbuf)[132] = (float(*)[132])(smem + 24576);     // 33.8 KB

    const int ar = tid >> 3, aq = tid & 7;
    const int sa = ldsw8(ar, aq);
    const int br0 = tid >> 3, bq0 = tid & 7;
    const int br1 = (tid + 512) >> 3, bq1 = tid & 7;
    const int sb0 = ldsw8(br0, bq0), sb1 = ldsw8(br1, bq1);

    const int lane = tid & 63;
    const int l15 = lane & 15;
    const int q = lane >> 4;
    const int wv = tid >> 6;
    const int wn = (wv & 3) * 32;

    for (int s = 0; s < 19; ++s) {
      unsigned* xc32 = (unsigned*)(xcat2 + (size_t)(s & 1) * 131072);
      unsigned* xn32 = (unsigned*)(xcat2 + (size_t)((s + 1) & 1) * 131072);
      const float* gx = gates_all_ + (size_t)s * 131072;
      unsigned* hb32 = (unsigned*)(hb + (size_t)s * 32768);

      if (s > 0) {
        if (tid < 16) {
          while (aldi(&fh[tid]) < s) __builtin_amdgcn_s_sleep(1);
        }
        __syncthreads();
      }

      floatx4 zero = {0.f, 0.f, 0.f, 0.f};
      floatx4 acc[4][2];
#pragma unroll
      for (int i = 0; i < 4; ++i)
#pragma unroll
        for (int j = 0; j < 2; ++j) acc[i][j] = zero;

#pragma unroll 1
      for (int ph = 0; ph < 2; ++ph) {
        if (ph == 1) {
          __syncthreads();
          if (tid < 64) {
            while (aldi(&fctx[tid]) < s + 1) __builtin_amdgcn_s_sleep(1);
          }
          __syncthreads();
        }
        const int kLo = ph * 512;
#pragma unroll 1
        for (int k0 = kLo; k0 < kLo + 512; k0 += 64) {
          // A (xcat, cross-block data) via coherent bypass loads
          const unsigned* ap = xc32 + (ar << 9) + (k0 >> 1) + aq * 4;
          unsigned au0 = ald(ap + 0);
          unsigned au1 = ald(ap + 1);
          unsigned au2 = ald(ap + 2);
          unsigned au3 = ald(ap + 3);
          // B (weights, block-private) via normal cached loads
          uint4 b0 = *(const uint4*)(Wgi + (size_t)(nBase + br0) * 1024 + k0 +
                                     bq0 * 8);
          uint4 b1 = *(const uint4*)(Wgi + (size_t)(nBase + br1) * 1024 + k0 +
                                     bq1 * 8);
          __syncthreads();
          {
            uint4 av;
            av.x = au0; av.y = au1; av.z = au2; av.w = au3;
            *(uint4*)&As[sa] = av;
          }
          *(uint4*)&Bs[sb0] = b0;
          *(uint4*)&Bs[sb1] = b1;
          __syncthreads();
          if (tid < 256) {
#pragma unroll
            for (int ks = 0; ks < 2; ++ks) {
              bf16x8 af[4], bfv[2];
#pragma unroll
              for (int i = 0; i < 4; ++i)
                af[i] = *(const bf16x8*)&As[ldsw8(i * 16 + l15, ks * 4 + q)];
#pragma unroll
              for (int j = 0; j < 2; ++j)
                bfv[j] =
                    *(const bf16x8*)&Bs[ldsw8(wn + j * 16 + l15, ks * 4 + q)];
#pragma unroll
              for (int i = 0; i < 4; ++i)
#pragma unroll
                for (int j = 0; j < 2; ++j)
                  acc[i][j] = __builtin_amdgcn_mfma_f32_16x16x32_bf16(
                      af[i], bfv[j], acc[i][j], 0, 0, 0);
            }
          }
        }
      }

      if (tid < 256) {
#pragma unroll
        for (int i = 0; i < 4; ++i)
#pragma unroll
          for (int j = 0; j < 2; ++j)
#pragma unroll
            for (int p = 0; p < 4; ++p)
              gbuf[i * 16 + q * 4 + p][wn + j * 16 + l15] = acc[i][j][p];
      }
      __syncthreads();

      // Pointwise: 1024 pairs (b, jp), 2 per thread; pack u32.
#pragma unroll
      for (int it = 0; it < 2; ++it) {
        int p = it * 512 + tid;
        int bb = p >> 4, jp = p & 15;
        float4 gv0 = *(float4*)&gbuf[bb][jp * 8];
        float4 gv1 = *(float4*)&gbuf[bb][jp * 8 + 4];
        const float* gxp = gx + (size_t)bb * 2048 + nBase + jp * 8;
        float4 gx0 = *(const float4*)(gxp);
        float4 gx1 = *(const float4*)(gxp + 4);
        int jg0 = (nBase >> 2) + jp * 2;
        float cv0 = c[bb * 512 + jg0];
        float cv1 = c[bb * 512 + jg0 + 1];
        float cn0 = sigmoid_fast(gv0.y + gx0.y) * cv0 +
                    sigmoid_fast(gv0.x + gx0.x) * tanh_fast(gv0.z + gx0.z);
        float hn0 = sigmoid_fast(gv0.w + gx0.w) * tanh_fast(cn0);
        float cn1 = sigmoid_fast(gv1.y + gx1.y) * cv1 +
                    sigmoid_fast(gv1.x + gx1.x) * tanh_fast(gv1.z + gx1.z);
        float hn1 = sigmoid_fast(gv1.w + gx1.w) * tanh_fast(cn1);
        c[bb * 512 + jg0] = cn0;
        c[bb * 512 + jg0 + 1] = cn1;
        unsigned pk = (unsigned)f2bf(hn0) | ((unsigned)f2bf(hn1) << 16);
        ast(xn32 + ((bb << 10) + jg0) / 2, pk);       // h -> next xcat (bypass)
        hb32[((bb << 9) + jg0) / 2] = pk;             // history (cached)
      }
      asm volatile("s_waitcnt vmcnt(0)" ::: "memory");
      __syncthreads();
      if (tid == 0) asti(&fh[g], s + 1);
    }
  }
}

// ---------------------------------------------------------------------------
// prep_all: ALL head work in one dispatch. Virtual-block grid-stride.
// ---------------------------------------------------------------------------
#define VB_ENCOUT 2512
#define VB_WGI    4080
#define VB_WB0I   4592
#define VB_ENCW   4848
#define VB_DECW   4912
#define VB_EMB    4976
#define VB_ZOUT   5136
#define VB_CZ     5449
#define VB_XCZ    5457
#define VB_HBPAD  5489
#define VB_BSUM   5493
#define VB_TOTAL  5494

struct PrepArgs {
  const float *fc_W, *enc_out, *W_ih, *W_hh, *b_ih, *b_hh, *enc_W, *dec_W, *emb;
  const int* captions;
  unsigned short *fcWb, *encOutb, *Wgi, *Wb0i, *encWb, *dec_Wp, *embxb, *hb,
      *xcat2;
  float *bsumi, *c, *out;
  int* flags;
};

__global__ __launch_bounds__(256) void prep_all(PrepArgs A) {
  const int tid = threadIdx.x;
  const uint4 z4 = {0u, 0u, 0u, 0u};
  for (int vb = blockIdx.x; vb < VB_TOTAL; vb += gridDim.x) {
    if (vb < VB_ENCOUT) {
      int base = vb * 4096;
#pragma unroll 4
      for (int i = 0; i < 16; ++i) {
        int idx = base + i * 256 + tid;
        int r = idx >> 9, cc = idx & 511;
        float v = (r < 20000) ? A.fc_W[(size_t)r * 512 + cc] : 0.f;
        A.fcWb[idx] = f2bf(v);
      }
    } else if (vb < VB_WGI) {
      int base = (vb - VB_ENCOUT) * 4096;
#pragma unroll 4
      for (int i = 0; i < 16; ++i) {
        int idx = base + i * 256 + tid;
        A.encOutb[idx] = f2bf(A.enc_out[idx]);
      }
    } else if (vb < VB_WB0I) {
      int base = (vb - VB_WGI) * 4096;
#pragma unroll 4
      for (int i = 0; i < 16; ++i) {
        int idx = base + i * 256 + tid;
        int np = idx >> 10, k = idx & 1023;
        int row = (np & 3) * 512 + (np >> 2);
        float v = (k < 512) ? A.W_hh[(size_t)row * 512 + k]
                            : A.W_ih[(size_t)row * 1024 + 512 + (k - 512)];
        A.Wgi[idx] = f2bf(v);
      }
    } else if (vb < VB_ENCW) {
      int base = (vb - VB_WB0I) * 4096;
#pragma unroll 4
      for (int i = 0; i < 16; ++i) {
        int idx = base + i * 256 + tid;
        int np = idx >> 9, k = idx & 511;
        int row = (np & 3) * 512 + (np >> 2);
        A.Wb0i[idx] = f2bf(A.W_ih[(size_t)row * 1024 + k]);
      }
    } else if (vb < VB_DECW) {
      int base = (vb - VB_ENCW) * 4096;
#pragma unroll 4
      for (int i = 0; i < 16; ++i) {
        int idx = base + i * 256 + tid;
        A.encWb[idx] = f2bf(A.enc_W[idx]);
      }
    } else if (vb < VB_EMB) {
      int base = (vb - VB_DECW) * 4096;
#pragma unroll 4
      for (int i = 0; i < 16; ++i) {
        int idx = base + i * 256 + tid;
        int kg = idx >> 12, rem = idx & 4095;
        int a = rem >> 3, j = rem & 7;
        A.dec_Wp[idx] = f2bf(A.dec_W[(size_t)a * 512 + kg * 8 + j]);
      }
    } else if (vb < VB_ZOUT) {
      int base = (vb - VB_EMB) * 4096;
#pragma unroll 4
      for (int i = 0; i < 16; ++i) {
        int idx = base + i * 256 + tid;
        int m = idx >> 9, cc = idx & 511;
        unsigned short r = 0;
        if (m < 1216) {
          int t = m >> 6, b = m & 63;
          int cap = A.captions[b * LL + t];
          r = f2bf(A.emb[(size_t)cap * 512 + cc]);
        }
        A.embxb[idx] = r;
      }
    } else if (vb < VB_CZ) {
      int u0 = (vb - VB_ZOUT) * 1024;
      floatx4 zf = {0.f, 0.f, 0.f, 0.f};
#pragma unroll
      for (int i = 0; i < 4; ++i) {
        int u = u0 + i * 256 + tid;
        if (u < 320000) {
          int b = u / 5000, v4 = u - b * 5000;
          *(floatx4*)(A.out + (size_t)b * ((size_t)LL * VV) + v4 * 4) = zf;
        }
      }
    } else if (vb < VB_XCZ) {
      int u0 = (vb - VB_CZ) * 1024;
      floatx4 zf = {0.f, 0.f, 0.f, 0.f};
#pragma unroll
      for (int i = 0; i < 4; ++i) {
        int u = u0 + i * 256 + tid;
        *(floatx4*)(A.c + (size_t)u * 4) = zf;
      }
    } else if (vb < VB_HBPAD) {
      int u0 = (vb - VB_XCZ) * 1024;
#pragma unroll
      for (int i = 0; i < 4; ++i) {
        int u = u0 + i * 256 + tid;
        ((uint4*)A.xcat2)[u] = z4;
      }
    } else if (vb < VB_BSUM) {
      int u0 = (vb - VB_HBPAD) * 1024;
      uint4* hp = (uint4*)(A.hb + (size_t)1216 * 512);
#pragma unroll
      for (int i = 0; i < 4; ++i) {
        int u = u0 + i * 256 + tid;
        hp[u] = z4;
      }
    } else {
#pragma unroll
      for (int i = 0; i < 8; ++i) {
        int e = i * 256 + tid;
        int row = (e & 3) * 512 + (e >> 2);
        A.bsumi[e] = A.b_ih[row] + A.b_hh[row];
        if (e < 80) A.flags[e] = 0;
      }
    }
  }
}

extern "C" void kernel_launch(void* const* d_in, const int* in_sizes, int n_in,
                              void* d_out, int out_size, void* d_ws, size_t ws_size,
                              hipStream_t stream) {
  const float* enc_out  = (const float*)d_in[0];
  const int*   captions = (const int*)d_in[1];
  const float* emb      = (const float*)d_in[2];
  const float* W_ih     = (const float*)d_in[3];
  const float* W_hh     = (const float*)d_in[4];
  const float* b_ih     = (const float*)d_in[5];
  const float* b_hh     = (const float*)d_in[6];
  const float* enc_W    = (const float*)d_in[7];
  const float* enc_b    = (const float*)d_in[8];
  const float* dec_W    = (const float*)d_in[9];
  const float* dec_b    = (const float*)d_in[10];
  const float* energy_W = (const float*)d_in[11];
  const float* energy_b = (const float*)d_in[12];
  const float* fc_W     = (const float*)d_in[13];
  const float* fc_b     = (const float*)d_in[14];
  float* out = (float*)d_out;

  // Workspace layout
  float* ws = (float*)d_ws;
  float* c          = ws;                                   // 64*512
  float* gates_all  = c + 32768;                            // 19*64*2048 (interleaved)
  float* bsumi      = gates_all + (size_t)19 * 131072;      // 2048
  int*   flags      = (int*)(bsumi + 2048);                 // 80
  unsigned short* enc_projb = (unsigned short*)(flags + 80);   // 12544*512
  unsigned short* fcWb    = enc_projb + (size_t)12544 * 512;   // 20096*512
  unsigned short* encWb   = fcWb + (size_t)20096 * 512;        // 512*512
  unsigned short* encOutb = encWb + (size_t)512 * 512;         // 12544*512
  unsigned short* Wb0i    = encOutb + (size_t)12544 * 512;     // 2048*512
  unsigned short* Wgi     = Wb0i + (size_t)2048 * 512;         // 2048*1024
  unsigned short* dec_Wp  = Wgi + (size_t)2048 * 1024;         // 512*512
  unsigned short* embxb   = dec_Wp + (size_t)512 * 512;        // 1280*512
  unsigned short* hb      = embxb + (size_t)1280 * 512;        // 1280*512
  unsigned short* xcat2   = hb + (size_t)1280 * 512;           // 2*128*1024

  PrepArgs pa;
  pa.fc_W = fc_W;     pa.enc_out = enc_out; pa.W_ih = W_ih;  pa.W_hh = W_hh;
  pa.b_ih = b_ih;     pa.b_hh = b_hh;       pa.enc_W = enc_W;
  pa.dec_W = dec_W;   pa.emb = emb;         pa.captions = captions;
  pa.fcWb = fcWb;     pa.encOutb = encOutb; pa.Wgi = Wgi;    pa.Wb0i = Wb0i;
  pa.encWb = encWb;   pa.dec_Wp = dec_Wp;   pa.embxb = embxb;
  pa.hb = hb;         pa.xcat2 = xcat2;     pa.bsumi = bsumi;
  pa.c = c;           pa.out = out;         pa.flags = flags;
  prep_all<<<2560, 256, 0, stream>>>(pa);

  // gates_x (interleaved) = embx @ Wb0i^T + bsumi   [MFMA]
  gemm_mfma_bt<<<dim3(16, 10), 256, 0, stream>>>(
      embxb, Wb0i, bsumi, gates_all, 1216, 2048, 512, 512, 2048, 0, 0);

  // enc_projb (bf16) = enc_out @ enc_W^T + enc_b   [MFMA, bf16 store]
  gemm_mfma_bt<<<dim3(4, 98), 256, 0, stream>>>(
      encOutb, encWb, enc_b, (float*)enc_projb, 12544, 512, 512, 512, 512, 2, 0);

  // Entire recurrent loop: ONE persistent dispatch (80 blocks, relaxed-flag
  // synced, caches never invalidated, enc_projb partially LDS-resident).
  decoder_persist<<<80, 512, 0, stream>>>(
      enc_projb, encOutb, dec_Wp, dec_b, energy_W, energy_b, Wgi, gates_all,
      c, xcat2, hb, flags);

  // Batched logits: out[b, t+1, :] = h @ fc_W^T + fc_b  [MFMA, XCD-grouped]
  gemm_mfma_bt<<<1600, 256, 0, stream>>>(
      hb, fcWb, fc_b, out, 1216, 20000, 512, 512, 0, 1, 2);
}

// Round 14
// 1275.574 us; speedup vs baseline: 1.5787x; 1.0459x over previous
//
#include <hip/hip_runtime.h>
#include <hip/hip_bf16.h>
#include <math.h>

// Problem dims (fixed)
#define B   64
#define NN  196
#define HH  512
#define EE  512
#define AA  512
#define VV  20000
#define LL  20

typedef __attribute__((ext_vector_type(8))) short bf16x8;
typedef __attribute__((ext_vector_type(4))) float floatx4;

__device__ __forceinline__ float tanh_fast(float x) {
  float e2 = __expf(2.f * x);
  return 1.f - 2.f / (e2 + 1.f);
}
__device__ __forceinline__ float sigmoid_fast(float x) {
  return 1.f / (1.f + __expf(-x));
}
__device__ __forceinline__ float bf2f(unsigned short u) {
  return __uint_as_float(((unsigned)u) << 16);
}
__device__ __forceinline__ unsigned short f2bf(float v) {
  __hip_bfloat16 h = __float2bfloat16(v);
  return *reinterpret_cast<unsigned short*>(&h);
}

// RELAXED agent-scope atomics: coherent, NO cache invalidate/writeback.
// (Round 12 proven: acquire/release invalidates cost 660 us over the loop.)
__device__ __forceinline__ unsigned ald(const unsigned* p) {
  return __hip_atomic_load(p, __ATOMIC_RELAXED, __HIP_MEMORY_SCOPE_AGENT);
}
__device__ __forceinline__ unsigned long long ald64(const unsigned long long* p) {
  return __hip_atomic_load(p, __ATOMIC_RELAXED, __HIP_MEMORY_SCOPE_AGENT);
}
__device__ __forceinline__ void ast(unsigned* p, unsigned v) {
  __hip_atomic_store(p, v, __ATOMIC_RELAXED, __HIP_MEMORY_SCOPE_AGENT);
}
__device__ __forceinline__ int aldi(const int* p) {
  return __hip_atomic_load(p, __ATOMIC_RELAXED, __HIP_MEMORY_SCOPE_AGENT);
}
__device__ __forceinline__ void asti(int* p, int v) {
  __hip_atomic_store(p, v, __ATOMIC_RELAXED, __HIP_MEMORY_SCOPE_AGENT);
}

// Chunk-XOR LDS slot for BK=32 rows (4 x 16B chunks). Measured: 0 conflicts.
__device__ __forceinline__ int ldsw(int row, int q4) {
  return (row * 4 + (q4 ^ ((row >> 1) & 3))) * 8;
}
// Chunk-XOR for 256-col rows (32 x 16B chunks): bijective per row; writes
// (8 consecutive chunks of one row) and ds_read_b128 reads (16 consecutive
// rows at fixed chunk) both hit distinct bank groups -> conflict-free.
__device__ __forceinline__ int ldsw32(int row, int q32) {
  return (row * 32 + (q32 ^ (row & 31))) * 8;
}

// ---------------------------------------------------------------------------
// bf16 MFMA GEMM (EXACT round-6/9/10 version; measured: logits 88us, FETCH
// 24MB, 0 conflicts). 128x128 tile, BK=32, 256 thr. gridMX==2: XCD-grouped.
// ---------------------------------------------------------------------------
__global__ __launch_bounds__(256) void gemm_mfma_bt(
    const unsigned short* __restrict__ Xb, const unsigned short* __restrict__ Wb,
    const float* __restrict__ bias, float* __restrict__ C,
    int M, int N, int K, int lda, int ldC, int outMode, int gridMX) {
  __shared__ unsigned short As[128 * 32];
  __shared__ unsigned short Bs[128 * 32];
  const int tid = threadIdx.x;
  const int lane = tid & 63;
  const int l15 = lane & 15;
  const int q = lane >> 4;
  const int wv = tid >> 6;
  const int wm = (wv >> 1) * 64;
  const int wn = (wv & 1) * 64;
  int mBase, nBase;
  if (gridMX == 2) {
    const int MT = (M + 127) >> 7, NT = (N + 127) >> 7;
    int wg = blockIdx.x;
    int xcd = wg & 7, idx = wg >> 3;
    int kk = idx / MT, mi = idx - kk * MT;
    int p = kk * 8 + xcd;
    if (p >= NT) return;
    mBase = mi * 128;
    nBase = p * 128;
  } else {
    mBase = blockIdx.y * 128;
    nBase = blockIdx.x * 128;
  }

  const int c0 = tid, c1 = tid + 256;
  const int r0 = c0 >> 2, q0 = c0 & 3;
  const int r1 = c1 >> 2, q1 = c1 & 3;
  const int s0 = ldsw(r0, q0), s1 = ldsw(r1, q1);

  floatx4 zero = {0.f, 0.f, 0.f, 0.f};
  floatx4 acc[4][4];
#pragma unroll
  for (int i = 0; i < 4; ++i)
#pragma unroll
    for (int j = 0; j < 4; ++j) acc[i][j] = zero;

  for (int k0 = 0; k0 < K; k0 += 32) {
    uint4 a0 = *(const uint4*)(Xb + (size_t)(mBase + r0) * lda + k0 + q0 * 8);
    uint4 a1 = *(const uint4*)(Xb + (size_t)(mBase + r1) * lda + k0 + q1 * 8);
    uint4 b0 = *(const uint4*)(Wb + (size_t)(nBase + r0) * K + k0 + q0 * 8);
    uint4 b1 = *(const uint4*)(Wb + (size_t)(nBase + r1) * K + k0 + q1 * 8);
    __syncthreads();
    *(uint4*)&As[s0] = a0;
    *(uint4*)&As[s1] = a1;
    *(uint4*)&Bs[s0] = b0;
    *(uint4*)&Bs[s1] = b1;
    __syncthreads();
    bf16x8 af[4], bfv[4];
#pragma unroll
    for (int i = 0; i < 4; ++i)
      af[i] = *(const bf16x8*)&As[ldsw(wm + i * 16 + l15, q)];
#pragma unroll
    for (int j = 0; j < 4; ++j)
      bfv[j] = *(const bf16x8*)&Bs[ldsw(wn + j * 16 + l15, q)];
#pragma unroll
    for (int i = 0; i < 4; ++i)
#pragma unroll
      for (int j = 0; j < 4; ++j)
        acc[i][j] = __builtin_amdgcn_mfma_f32_16x16x32_bf16(af[i], bfv[j],
                                                            acc[i][j], 0, 0, 0);
  }

#pragma unroll
  for (int i = 0; i < 4; ++i) {
#pragma unroll
    for (int j = 0; j < 4; ++j) {
#pragma unroll
      for (int p = 0; p < 4; ++p) {
        int m = mBase + wm + i * 16 + q * 4 + p;
        int n = nBase + wn + j * 16 + l15;
        if (m < M && n < N) {
          float v = acc[i][j][p];
          if (bias) v += bias[n];
          if (outMode == 1) {
            size_t idx = (size_t)(m & 63) * ((size_t)LL * VV) +
                         (size_t)((m >> 6) + 1) * VV + n;
            C[idx] = v;
          } else if (outMode == 2) {
            ((unsigned short*)C)[(size_t)m * ldC + n] = f2bf(v);
          } else {
            C[(size_t)m * ldC + n] = v;
          }
        }
      }
    }
  }
}

// ---------------------------------------------------------------------------
// decoder_persist v4: ALL 19 steps, ONE dispatch, 96 blocks x 512 thr
// (64 attention producers + 32 gates consumers; co-resident on 256 CUs).
// Relaxed-atomic protocol (round 12, proven). New vs v3 (latency attack —
// round 13 showed loop is latency-bound, not BW-bound):
//  - Consumer GEMM chunk-burst: K=256 chunks; whole A-chunk (8 x 64-bit sc1)
//    + B-chunk (4 x uint4 cached) burst to registers in ONE latency exposure,
//    then 1 barrier -> LDS -> 1 barrier -> 8 barrier-free MFMA sub-iters.
//    Exposures/step 16 -> 4; barriers 32 -> 8.
//  - 32 consumers x 64 cols (was 16 x 128): per-block GEMM time halved.
//  - dec matvec: 2 interleaved accumulators (halves FMA dep chain).
// ---------------------------------------------------------------------------
__global__ __launch_bounds__(512) void decoder_persist(
    const unsigned short* __restrict__ enc_projb,
    const unsigned short* __restrict__ encOutb,
    const unsigned short* __restrict__ dec_Wp,  // [(k/8)*512+a] 8-chunk bf16
    const float* __restrict__ dec_b, const float* __restrict__ eW,
    const float* __restrict__ eb,
    const unsigned short* __restrict__ Wgi,     // [2048][1024] interleaved
    const float* __restrict__ gates_all_,       // [19][64][2048] interleaved
    float* __restrict__ c,
    unsigned short* __restrict__ xcat2,         // 2 x [128][1024] bf16
    unsigned short* __restrict__ hb,            // [1280][512] bf16
    int* __restrict__ flags) {                  // [0..63]=fctx, [64..95]=fh
  const int tid = threadIdx.x;
  __shared__ __align__(16) char smem[153600];
  int* fctx = flags;
  int* fh = flags + 64;

  if (blockIdx.x < 64) {
    // ======================= ATTENTION PRODUCER =======================
    const int b = blockIdx.x;
    unsigned short* projL = (unsigned short*)smem;  // 128 rows x 1KB = 131072
    float* hs = (float*)(smem + 131072);            // 2048
    float* sdec = (float*)(smem + 133120);          // 2048
    float* sw = (float*)(smem + 135168);            // 1024 (196 used)
    float* tmp = (float*)(smem + 136192);           // 1024
    float* cpR = (float*)(smem + 137216);           // 8*512*4 = 16384
    const int wvv = tid >> 6, lane = tid & 63;
    float ew8[8];
#pragma unroll
    for (int j = 0; j < 8; ++j) ew8[j] = eW[lane * 8 + j];
    float eb0 = eb[0];
    float dbv = dec_b[tid];

    // Persist enc_projb rows [0,128) in LDS once (reused all 19 steps)
    {
      const uint4* src = (const uint4*)(enc_projb + (size_t)b * NN * 512);
      uint4* dst = (uint4*)projL;
      for (int i = tid; i < 128 * 64; i += 512) dst[i] = src[i];
    }

    for (int s = 0; s < 19; ++s) {
      unsigned* xc32 = (unsigned*)(xcat2 + (size_t)(s & 1) * 131072);
      if (s > 0) {
        if (tid < 32) {
          while (aldi(&fh[tid]) < s) __builtin_amdgcn_s_sleep(1);
        }
        __syncthreads();
        // h (written by consumers) via coherent bypass loads
        if (tid < 256) {
          unsigned u = ald(xc32 + (b << 9) + tid);
          hs[2 * tid] = bf2f((unsigned short)(u & 0xffffu));
          hs[2 * tid + 1] = bf2f((unsigned short)(u >> 16));
        }
        __syncthreads();
        // dec matvec, 2 interleaved accumulators (halved dep chain)
        float d0 = dbv, d1 = 0.f;
#pragma unroll 2
        for (int kg = 0; kg < 64; kg += 2) {
          bf16x8 wa = *(const bf16x8*)(dec_Wp + (size_t)((kg << 9) + tid) * 8);
          bf16x8 wb =
              *(const bf16x8*)(dec_Wp + (size_t)(((kg + 1) << 9) + tid) * 8);
#pragma unroll
          for (int j = 0; j < 8; ++j) {
            d0 += hs[kg * 8 + j] * bf2f((unsigned short)wa[j]);
            d1 += hs[(kg + 1) * 8 + j] * bf2f((unsigned short)wb[j]);
          }
        }
        sdec[tid] = d0 + d1;
      } else {
        sdec[tid] = dbv;  // h_0 = 0
      }
      __syncthreads();

      float sd8[8];
#pragma unroll
      for (int j = 0; j < 8; ++j) sd8[j] = sdec[lane * 8 + j];
      // scores: LDS-resident rows [0,128)
      for (int n = wvv; n < 128; n += 8) {
        bf16x8 v8 = *(const bf16x8*)&projL[n * 512 + lane * 8];
        float a = 0.f;
#pragma unroll
        for (int j = 0; j < 8; ++j)
          a += tanh_fast(bf2f((unsigned short)v8[j]) + sd8[j]) * ew8[j];
#pragma unroll
        for (int off = 32; off; off >>= 1) a += __shfl_down(a, off, 64);
        if (lane == 0) sw[n] = a + eb0;
      }
      // scores: streamed rows [128,196) with 1-deep prefetch (L2-warm)
      {
        const unsigned short* epb =
            enc_projb + (size_t)b * NN * 512 + lane * 8;
        int n = 128 + wvv;
        bf16x8 v8 = *(const bf16x8*)(epb + (size_t)n * 512);
#pragma unroll 1
        while (true) {
          int n2 = n + 8;
          bf16x8 vnx = v8;
          if (n2 < NN) vnx = *(const bf16x8*)(epb + (size_t)n2 * 512);
          float a = 0.f;
#pragma unroll
          for (int j = 0; j < 8; ++j)
            a += tanh_fast(bf2f((unsigned short)v8[j]) + sd8[j]) * ew8[j];
#pragma unroll
          for (int off = 32; off; off >>= 1) a += __shfl_down(a, off, 64);
          if (lane == 0) sw[n] = a + eb0;
          v8 = vnx;
          n = n2;
          if (n >= NN) break;
        }
      }
      __syncthreads();

      // softmax over N
      float v = (tid < NN) ? sw[tid] : -1e30f;
      if (tid < 256) tmp[tid] = v;
      __syncthreads();
      for (int st = 128; st; st >>= 1) {
        if (tid < st) tmp[tid] = fmaxf(tmp[tid], tmp[tid + st]);
        __syncthreads();
      }
      float mx = tmp[0];
      __syncthreads();
      float e = (tid < NN) ? __expf(v - mx) : 0.f;
      if (tid < 256) tmp[tid] = e;
      __syncthreads();
      for (int st = 128; st; st >>= 1) {
        if (tid < st) tmp[tid] += tmp[tid + st];
        __syncthreads();
      }
      float inv = 1.f / tmp[0];
      if (tid < NN) sw[tid] = e * inv;
      __syncthreads();

      // ctx: 8 n-stripes x 64 col-groups, 16B/lane loads, 1-deep prefetch
      {
        const int st = tid >> 6;   // n-stripe (uniform per wave)
        const int cg = tid & 63;   // col group: cols cg*8 .. cg*8+7
        float a[8] = {0.f, 0.f, 0.f, 0.f, 0.f, 0.f, 0.f, 0.f};
        const unsigned short* eo =
            encOutb + (size_t)b * NN * 512 + cg * 8;
        int n = st;
        bf16x8 v8 = *(const bf16x8*)(eo + (size_t)n * 512);
#pragma unroll 1
        while (true) {
          int n2 = n + 8;
          bf16x8 vnx = v8;
          if (n2 < NN) vnx = *(const bf16x8*)(eo + (size_t)n2 * 512);
          float w = sw[n];
#pragma unroll
          for (int j = 0; j < 8; ++j)
            a[j] += w * bf2f((unsigned short)v8[j]);
          v8 = vnx;
          n = n2;
          if (n >= NN) break;
        }
        floatx4 a0v = {a[0], a[1], a[2], a[3]};
        floatx4 a1v = {a[4], a[5], a[6], a[7]};
        *(floatx4*)&cpR[st * 512 + cg * 8] = a0v;
        *(floatx4*)&cpR[st * 512 + cg * 8 + 4] = a1v;
      }
      __syncthreads();
      if (tid < 256) {
        float v0 = 0.f, v1 = 0.f;
#pragma unroll
        for (int st = 0; st < 8; ++st) {
          v0 += cpR[st * 512 + 2 * tid];
          v1 += cpR[st * 512 + 2 * tid + 1];
        }
        unsigned pk = (unsigned)f2bf(v0) | ((unsigned)f2bf(v1) << 16);
        ast(xc32 + (b << 9) + 256 + tid, pk);
      }
      asm volatile("s_waitcnt vmcnt(0)" ::: "memory");
      __syncthreads();
      if (tid == 0) asti(&fctx[b], s + 1);
    }
  } else {
    // ======================= GATES CONSUMER =======================
    const int g = blockIdx.x - 64;          // 0..31
    const int nBase = g * 64;               // interleaved col base (global)
    unsigned short* As = (unsigned short*)smem;            // [64][256] 32 KB
    unsigned short* Bs = (unsigned short*)(smem + 32768);  // [64][256] 32 KB
    float(*gbuf)[68] = (float(*)[68])(smem + 65536);       // 64*68*4 ~ 17 KB

    // chunk staging: 2048 16B-chunks per 64x256 tile; 4 per thread
    int cr[4], cq[4], cs[4];
#pragma unroll
    for (int i = 0; i < 4; ++i) {
      int ci = tid + i * 512;
      cr[i] = ci >> 5;
      cq[i] = ci & 31;
      cs[i] = ldsw32(cr[i], cq[i]);
    }

    const int lane = tid & 63;
    const int l15 = lane & 15;
    const int q = lane >> 4;
    const int wv = tid >> 6;
    const int wn = (wv & 3) * 16;  // MFMA waves 0..3 own 16-col slices

    for (int s = 0; s < 19; ++s) {
      const unsigned long long* xc64 =
          (const unsigned long long*)(xcat2 + (size_t)(s & 1) * 131072);
      unsigned* xn32 = (unsigned*)(xcat2 + (size_t)((s + 1) & 1) * 131072);
      const float* gx = gates_all_ + (size_t)s * 131072;
      unsigned* hb32 = (unsigned*)(hb + (size_t)s * 32768);

      if (s > 0) {
        if (tid < 32) {
          while (aldi(&fh[tid]) < s) __builtin_amdgcn_s_sleep(1);
        }
        __syncthreads();
      }

      floatx4 zero = {0.f, 0.f, 0.f, 0.f};
      floatx4 acc[4];
#pragma unroll
      for (int i = 0; i < 4; ++i) acc[i] = zero;

#pragma unroll 1
      for (int ph = 0; ph < 2; ++ph) {
        if (ph == 1) {
          __syncthreads();
          if (tid < 64) {
            while (aldi(&fctx[tid]) < s + 1) __builtin_amdgcn_s_sleep(1);
          }
          __syncthreads();
        }
#pragma unroll 1
        for (int kc = 0; kc < 2; ++kc) {
          const int kcB = ph * 512 + kc * 256;  // bf16 col base
          // ---- burst load: whole 64x256 A-chunk + B-chunk to registers ----
          unsigned long long a64[8];
          uint4 bv[4];
#pragma unroll
          for (int i = 0; i < 4; ++i) {
            const unsigned long long* ap =
                xc64 + (size_t)cr[i] * 256 + (kcB >> 2) + cq[i] * 2;
            a64[2 * i] = ald64(ap);
            a64[2 * i + 1] = ald64(ap + 1);
            bv[i] = *(const uint4*)(Wgi + (size_t)(nBase + cr[i]) * 1024 +
                                    kcB + cq[i] * 8);
          }
          __syncthreads();
#pragma unroll
          for (int i = 0; i < 4; ++i) {
            *(unsigned long long*)&As[cs[i]] = a64[2 * i];
            *(unsigned long long*)&As[cs[i] + 4] = a64[2 * i + 1];
            *(uint4*)&Bs[cs[i]] = bv[i];
          }
          __syncthreads();
          // ---- 8 barrier-free MFMA sub-iterations over the chunk ----
          if (wv < 4) {
#pragma unroll
            for (int k0s = 0; k0s < 8; ++k0s) {
              bf16x8 bfv = *(const bf16x8*)&Bs[ldsw32(wn + l15, k0s * 4 + q)];
#pragma unroll
              for (int i = 0; i < 4; ++i) {
                bf16x8 af =
                    *(const bf16x8*)&As[ldsw32(i * 16 + l15, k0s * 4 + q)];
                acc[i] = __builtin_amdgcn_mfma_f32_16x16x32_bf16(af, bfv,
                                                                 acc[i], 0, 0, 0);
              }
            }
          }
        }
      }

      if (wv < 4) {
#pragma unroll
        for (int i = 0; i < 4; ++i)
#pragma unroll
          for (int p = 0; p < 4; ++p)
            gbuf[i * 16 + q * 4 + p][wn + l15] = acc[i][p];
      }
      __syncthreads();

      // Pointwise: 512 units, 1/thread; each = 2 adjacent h cols of one b.
      {
        int bb = tid >> 3, jp = tid & 7;
        float4 gv0 = *(float4*)&gbuf[bb][jp * 8];
        float4 gv1 = *(float4*)&gbuf[bb][jp * 8 + 4];
        const float* gxp = gx + (size_t)bb * 2048 + nBase + jp * 8;
        float4 gx0 = *(const float4*)(gxp);
        float4 gx1 = *(const float4*)(gxp + 4);
        int jg0 = (nBase >> 2) + jp * 2;  // = g*16 + jp*2
        float cv0 = c[bb * 512 + jg0];
        float cv1 = c[bb * 512 + jg0 + 1];
        float cn0 = sigmoid_fast(gv0.y + gx0.y) * cv0 +
                    sigmoid_fast(gv0.x + gx0.x) * tanh_fast(gv0.z + gx0.z);
        float hn0 = sigmoid_fast(gv0.w + gx0.w) * tanh_fast(cn0);
        float cn1 = sigmoid_fast(gv1.y + gx1.y) * cv1 +
                    sigmoid_fast(gv1.x + gx1.x) * tanh_fast(gv1.z + gx1.z);
        float hn1 = sigmoid_fast(gv1.w + gx1.w) * tanh_fast(cn1);
        c[bb * 512 + jg0] = cn0;
        c[bb * 512 + jg0 + 1] = cn1;
        unsigned pk = (unsigned)f2bf(hn0) | ((unsigned)f2bf(hn1) << 16);
        ast(xn32 + (((bb << 10) + jg0) >> 1), pk);  // h -> next xcat (bypass)
        hb32[((bb << 9) + jg0) >> 1] = pk;          // history (cached)
      }
      asm volatile("s_waitcnt vmcnt(0)" ::: "memory");
      __syncthreads();
      if (tid == 0) asti(&fh[g], s + 1);
    }
  }
}

// ---------------------------------------------------------------------------
// prep_all: ALL head work in one dispatch. Virtual-block grid-stride.
// ---------------------------------------------------------------------------
#define VB_ENCOUT 2512
#define VB_WGI    4080
#define VB_WB0I   4592
#define VB_ENCW   4848
#define VB_DECW   4912
#define VB_EMB    4976
#define VB_ZOUT   5136
#define VB_CZ     5449
#define VB_XCZ    5457
#define VB_HBPAD  5489
#define VB_BSUM   5493
#define VB_TOTAL  5494

struct PrepArgs {
  const float *fc_W, *enc_out, *W_ih, *W_hh, *b_ih, *b_hh, *enc_W, *dec_W, *emb;
  const int* captions;
  unsigned short *fcWb, *encOutb, *Wgi, *Wb0i, *encWb, *dec_Wp, *embxb, *hb,
      *xcat2;
  float *bsumi, *c, *out;
  int* flags;
};

__global__ __launch_bounds__(256) void prep_all(PrepArgs A) {
  const int tid = threadIdx.x;
  const uint4 z4 = {0u, 0u, 0u, 0u};
  for (int vb = blockIdx.x; vb < VB_TOTAL; vb += gridDim.x) {
    if (vb < VB_ENCOUT) {
      int base = vb * 4096;
#pragma unroll 4
      for (int i = 0; i < 16; ++i) {
        int idx = base + i * 256 + tid;
        int r = idx >> 9, cc = idx & 511;
        float v = (r < 20000) ? A.fc_W[(size_t)r * 512 + cc] : 0.f;
        A.fcWb[idx] = f2bf(v);
      }
    } else if (vb < VB_WGI) {
      int base = (vb - VB_ENCOUT) * 4096;
#pragma unroll 4
      for (int i = 0; i < 16; ++i) {
        int idx = base + i * 256 + tid;
        A.encOutb[idx] = f2bf(A.enc_out[idx]);
      }
    } else if (vb < VB_WB0I) {
      int base = (vb - VB_WGI) * 4096;
#pragma unroll 4
      for (int i = 0; i < 16; ++i) {
        int idx = base + i * 256 + tid;
        int np = idx >> 10, k = idx & 1023;
        int row = (np & 3) * 512 + (np >> 2);
        float v = (k < 512) ? A.W_hh[(size_t)row * 512 + k]
                            : A.W_ih[(size_t)row * 1024 + 512 + (k - 512)];
        A.Wgi[idx] = f2bf(v);
      }
    } else if (vb < VB_ENCW) {
      int base = (vb - VB_WB0I) * 4096;
#pragma unroll 4
      for (int i = 0; i < 16; ++i) {
        int idx = base + i * 256 + tid;
        int np = idx >> 9, k = idx & 511;
        int row = (np & 3) * 512 + (np >> 2);
        A.Wb0i[idx] = f2bf(A.W_ih[(size_t)row * 1024 + k]);
      }
    } else if (vb < VB_DECW) {
      int base = (vb - VB_ENCW) * 4096;
#pragma unroll 4
      for (int i = 0; i < 16; ++i) {
        int idx = base + i * 256 + tid;
        A.encWb[idx] = f2bf(A.enc_W[idx]);
      }
    } else if (vb < VB_EMB) {
      int base = (vb - VB_DECW) * 4096;
#pragma unroll 4
      for (int i = 0; i < 16; ++i) {
        int idx = base + i * 256 + tid;
        int kg = idx >> 12, rem = idx & 4095;
        int a = rem >> 3, j = rem & 7;
        A.dec_Wp[idx] = f2bf(A.dec_W[(size_t)a * 512 + kg * 8 + j]);
      }
    } else if (vb < VB_ZOUT) {
      int base = (vb - VB_EMB) * 4096;
#pragma unroll 4
      for (int i = 0; i < 16; ++i) {
        int idx = base + i * 256 + tid;
        int m = idx >> 9, cc = idx & 511;
        unsigned short r = 0;
        if (m < 1216) {
          int t = m >> 6, b = m & 63;
          int cap = A.captions[b * LL + t];
          r = f2bf(A.emb[(size_t)cap * 512 + cc]);
        }
        A.embxb[idx] = r;
      }
    } else if (vb < VB_CZ) {
      int u0 = (vb - VB_ZOUT) * 1024;
      floatx4 zf = {0.f, 0.f, 0.f, 0.f};
#pragma unroll
      for (int i = 0; i < 4; ++i) {
        int u = u0 + i * 256 + tid;
        if (u < 320000) {
          int b = u / 5000, v4 = u - b * 5000;
          *(floatx4*)(A.out + (size_t)b * ((size_t)LL * VV) + v4 * 4) = zf;
        }
      }
    } else if (vb < VB_XCZ) {
      int u0 = (vb - VB_CZ) * 1024;
      floatx4 zf = {0.f, 0.f, 0.f, 0.f};
#pragma unroll
      for (int i = 0; i < 4; ++i) {
        int u = u0 + i * 256 + tid;
        *(floatx4*)(A.c + (size_t)u * 4) = zf;
      }
    } else if (vb < VB_HBPAD) {
      int u0 = (vb - VB_XCZ) * 1024;
#pragma unroll
      for (int i = 0; i < 4; ++i) {
        int u = u0 + i * 256 + tid;
        ((uint4*)A.xcat2)[u] = z4;
      }
    } else if (vb < VB_BSUM) {
      int u0 = (vb - VB_HBPAD) * 1024;
      uint4* hp = (uint4*)(A.hb + (size_t)1216 * 512);
#pragma unroll
      for (int i = 0; i < 4; ++i) {
        int u = u0 + i * 256 + tid;
        hp[u] = z4;
      }
    } else {
#pragma unroll
      for (int i = 0; i < 8; ++i) {
        int e = i * 256 + tid;
        int row = (e & 3) * 512 + (e >> 2);
        A.bsumi[e] = A.b_ih[row] + A.b_hh[row];
        if (e < 96) A.flags[e] = 0;
      }
    }
  }
}

extern "C" void kernel_launch(void* const* d_in, const int* in_sizes, int n_in,
                              void* d_out, int out_size, void* d_ws, size_t ws_size,
                              hipStream_t stream) {
  const float* enc_out  = (const float*)d_in[0];
  const int*   captions = (const int*)d_in[1];
  const float* emb      = (const float*)d_in[2];
  const float* W_ih     = (const float*)d_in[3];
  const float* W_hh     = (const float*)d_in[4];
  const float* b_ih     = (const float*)d_in[5];
  const float* b_hh     = (const float*)d_in[6];
  const float* enc_W    = (const float*)d_in[7];
  const float* enc_b    = (const float*)d_in[8];
  const float* dec_W    = (const float*)d_in[9];
  const float* dec_b    = (const float*)d_in[10];
  const float* energy_W = (const float*)d_in[11];
  const float* energy_b = (const float*)d_in[12];
  const float* fc_W     = (const float*)d_in[13];
  const float* fc_b     = (const float*)d_in[14];
  float* out = (float*)d_out;

  // Workspace layout
  float* ws = (float*)d_ws;
  float* c          = ws;                                   // 64*512
  float* gates_all  = c + 32768;                            // 19*64*2048 (interleaved)
  float* bsumi      = gates_all + (size_t)19 * 131072;      // 2048
  int*   flags      = (int*)(bsumi + 2048);                 // 96
  unsigned short* enc_projb = (unsigned short*)(flags + 96);   // 12544*512
  unsigned short* fcWb    = enc_projb + (size_t)12544 * 512;   // 20096*512
  unsigned short* encWb   = fcWb + (size_t)20096 * 512;        // 512*512
  unsigned short* encOutb = encWb + (size_t)512 * 512;         // 12544*512
  unsigned short* Wb0i    = encOutb + (size_t)12544 * 512;     // 2048*512
  unsigned short* Wgi     = Wb0i + (size_t)2048 * 512;         // 2048*1024
  unsigned short* dec_Wp  = Wgi + (size_t)2048 * 1024;         // 512*512
  unsigned short* embxb   = dec_Wp + (size_t)512 * 512;        // 1280*512
  unsigned short* hb      = embxb + (size_t)1280 * 512;        // 1280*512
  unsigned short* xcat2   = hb + (size_t)1280 * 512;           // 2*128*1024

  PrepArgs pa;
  pa.fc_W = fc_W;     pa.enc_out = enc_out; pa.W_ih = W_ih;  pa.W_hh = W_hh;
  pa.b_ih = b_ih;     pa.b_hh = b_hh;       pa.enc_W = enc_W;
  pa.dec_W = dec_W;   pa.emb = emb;         pa.captions = captions;
  pa.fcWb = fcWb;     pa.encOutb = encOutb; pa.Wgi = Wgi;    pa.Wb0i = Wb0i;
  pa.encWb = encWb;   pa.dec_Wp = dec_Wp;   pa.embxb = embxb;
  pa.hb = hb;         pa.xcat2 = xcat2;     pa.bsumi = bsumi;
  pa.c = c;           pa.out = out;         pa.flags = flags;
  prep_all<<<2560, 256, 0, stream>>>(pa);

  // gates_x (interleaved) = embx @ Wb0i^T + bsumi   [MFMA]
  gemm_mfma_bt<<<dim3(16, 10), 256, 0, stream>>>(
      embxb, Wb0i, bsumi, gates_all, 1216, 2048, 512, 512, 2048, 0, 0);

  // enc_projb (bf16) = enc_out @ enc_W^T + enc_b   [MFMA, bf16 store]
  gemm_mfma_bt<<<dim3(4, 98), 256, 0, stream>>>(
      encOutb, encWb, enc_b, (float*)enc_projb, 12544, 512, 512, 512, 512, 2, 0);

  // Entire recurrent loop: ONE persistent dispatch (96 blocks: 64 producers +
  // 32 consumers; relaxed-flag synced, caches never invalidated).
  decoder_persist<<<96, 512, 0, stream>>>(
      enc_projb, encOutb, dec_Wp, dec_b, energy_W, energy_b, Wgi, gates_all,
      c, xcat2, hb, flags);

  // Batched logits: out[b, t+1, :] = h @ fc_W^T + fc_b  [MFMA, XCD-grouped]
  gemm_mfma_bt<<<1600, 256, 0, stream>>>(
      hb, fcWb, fc_b, out, 1216, 20000, 512, 512, 0, 1, 2);
}